// Round 3
// baseline (25624.020 us; speedup 1.0000x reference)
//
#include <hip/hip_runtime.h>
#include <hip/hip_bf16.h>

// Problem constants
constexpr int Bn = 256, Tn = 200, Dn = 32, Hn = 512, PHn = 256, PREPn = 16;
constexpr int COVn = 32, COVHn = 128, CLFHn = 64;
constexpr float DTc = 0.05f;
constexpr int NT = 512;   // threads per block
// grid = Bn = 256 blocks (one per CU); block g owns H-columns {2g,2g+1} and batch row g.

typedef _Float16 h2v __attribute__((ext_vector_type(2)));

// ---- packed f16 quad layout for streamed matrices: elem (k,j) of [N,K] at ((k>>3)*N + j)*8 + (k&7)
constexpr int PK_WP1   = 0;        // 256x512
constexpr int PK_WP2   = 131072;   // 64x256
constexpr int PK_WCLF1 = 147456;   // 64x512
constexpr int PK_TOTAL = 180224;

// ---- ws byte offsets (activations etc.)
constexpr size_t WS_HA  = 393216;   // f16 [256r x 512k] quad-transposed
constexpr size_t WS_HB  = 655360;   // f16
constexpr size_t WS_RH  = 917504;   // f16
constexpr size_t WS_GI  = 1179648;  // f16
constexpr size_t WS_HAF = 1441792;  // f32 row-major [256][512] (precise h carry)
constexpr size_t WS_OBS = 1966080;  // f32 [256]
constexpr size_t WS_BAR = 1967104;  // 2 x unsigned: cnt, gen

__device__ __forceinline__ float sigmoidf(float x) { return 1.0f / (1.0f + __expf(-x)); }

__device__ __forceinline__ float fdot2(unsigned w, unsigned v, float acc) {
#if __has_builtin(__builtin_amdgcn_fdot2)
  return __builtin_amdgcn_fdot2(__builtin_bit_cast(h2v, w),
                                __builtin_bit_cast(h2v, v), acc, false);
#else
  h2v a = __builtin_bit_cast(h2v, w), b = __builtin_bit_cast(h2v, v);
  return acc + (float)a.x * (float)b.x + (float)a.y * (float)b.y;
#endif
}
__device__ __forceinline__ float dotq(uint4 w, uint4 h, float acc) {
  acc = fdot2(w.x, h.x, acc); acc = fdot2(w.y, h.y, acc);
  acc = fdot2(w.z, h.z, acc); acc = fdot2(w.w, h.w, acc);
  return acc;
}
__device__ __forceinline__ unsigned pack2(float a, float b) {
  h2v h; h.x = (_Float16)a; h.y = (_Float16)b;
  return __builtin_bit_cast(unsigned, h);
}
// quad-transposed element index for activation matrices [256 rows x K]
__device__ __forceinline__ int qidx(int r, int k) { return ((k >> 3) * Bn + r) * 8 + (k & 7); }

// ---------------- prep: pack Wp1/Wp2/Wclf1 to f16 quads; zero barrier state ----------------
struct PrepArgs { const float *Wp1, *Wp2, *Wclf1; _Float16* dst; unsigned* bar; };

__global__ void prep_pack_kernel(PrepArgs a) {
  const int idx = blockIdx.x * 256 + threadIdx.x;
  if (idx == 0) { a.bar[0] = 0u; a.bar[1] = 0u; }
  if (idx >= PK_TOTAL) return;
  int off, N, K; const float* src;
  if      (idx < PK_WP2)   { off = PK_WP1;   N = 256; K = 512; src = a.Wp1; }
  else if (idx < PK_WCLF1) { off = PK_WP2;   N = 64;  K = 256; src = a.Wp2; }
  else                     { off = PK_WCLF1; N = 64;  K = 512; src = a.Wclf1; }
  const int li = idx - off, e = li & 7, t2 = li >> 3, j = t2 % N, k8 = t2 / N;
  a.dst[idx] = (_Float16)src[(size_t)j * K + k8 * 8 + e];
}

// ---------------- main cooperative-style persistent kernel ----------------
struct CoopArgs {
  const float *cov, *X, *M;
  const float *Wc1, *bc1, *Wc2, *bc2;
  const float *Whr, *Whz, *Whh;
  const float *bp1, *bp2;
  const float *w_prep, *bias_prep;
  const float *W_ih, *W_hh, *b_ih, *b_hh;
  const float *bclf1, *Wclf2, *bclf2;
  const uint4 *Wp1Q, *Wp2Q, *Wclf1Q;
  _Float16 *hA, *hB, *rh, *gi;
  float *hAf, *obs;
  unsigned* bar;
  float* out;
};

__device__ __forceinline__ void grid_barrier(unsigned* bar, unsigned& mygen) {
  __syncthreads();
  if (threadIdx.x == 0) {
    unsigned old = __hip_atomic_fetch_add(&bar[0], 1u, __ATOMIC_ACQ_REL, __HIP_MEMORY_SCOPE_AGENT);
    if (old == (unsigned)(Bn - 1)) {
      __hip_atomic_store(&bar[0], 0u, __ATOMIC_RELAXED, __HIP_MEMORY_SCOPE_AGENT);
      __hip_atomic_fetch_add(&bar[1], 1u, __ATOMIC_ACQ_REL, __HIP_MEMORY_SCOPE_AGENT);
    } else {
      while (__hip_atomic_load(&bar[1], __ATOMIC_ACQUIRE, __HIP_MEMORY_SCOPE_AGENT) == mygen)
        __builtin_amdgcn_s_sleep(2);
    }
  }
  mygen += 1;
  __syncthreads();
}

__device__ __forceinline__ void do_clf(const CoopArgs& a, const float* bclfL,
                                       const float* wclf2L, float bclf2r,
                                       int g, int tid, int tout) {
  if (tid < CLFHn) {
    const uint4* hAQ = (const uint4*)a.hA;
    float acc = bclfL[tid];
    #pragma unroll 4
    for (int q = 0; q < Hn / 8; ++q)
      acc = dotq(a.Wclf1Q[q * CLFHn + tid], hAQ[q * Bn + g], acc);
    float cc = fmaxf(acc, 0.0f) * wclf2L[tid];
    #pragma unroll
    for (int off = 32; off; off >>= 1) cc += __shfl_down(cc, off, 64);
    if (tid == 0) a.out[tout * Bn + g] = cc + bclf2r;
  }
}

__global__ __launch_bounds__(NT)
void gruode_coop(CoopArgs a) {
  const int g   = blockIdx.x;
  const int tid = threadIdx.x;
  const int ci  = tid >> 8;      // which of the 2 owned columns
  const int r   = tid & 255;     // batch row for column-phases
  const int c   = 2 * g + ci;    // owned H column

  // LDS-resident weight slices (persist across all 200 steps)
  __shared__ __align__(16) uint4 WhrL[2][64], WhzL[2][64], WhhL[2][64];   // 6 KB
  __shared__ __align__(16) uint4 WihL[2][3][64], Wh2L[2][3][64];          // 12 KB
  __shared__ __align__(16) uint4 hrowL[64];
  __shared__ __align__(16) uint4 qrowL[32];
  __shared__ float pL[2 * Dn];
  __shared__ float xrowL[Dn], mrowL[Dn];
  __shared__ float wprepL[Dn * 4 * PREPn];   // 8 KB
  __shared__ float bprepL[Dn * PREPn];       // 2 KB
  __shared__ float bp1L[PHn], bp2L[2 * Dn];
  __shared__ float bclfL[CLFHn], wclf2L[CLFHn];
  __shared__ float bgL[12];
  __shared__ float t1L[COVHn], covL[COVn];

  const uint4* hAQ = (const uint4*)a.hA;
  const uint4* hBQ = (const uint4*)a.hB;
  const uint4* rhQ = (const uint4*)a.rh;
  const uint4* giQ = (const uint4*)a.gi;

  // ---- one-time init: stage owned weight slices f32 -> f16 quads in LDS ----
  for (int n = tid; n < 1152; n += NT) {
    const float* srcrow; uint4* dst; int q;
    if (n < 384) {
      const int m = n >> 7, rem = n & 127, ci2 = rem >> 6; q = rem & 63;
      const float* W = (m == 0) ? a.Whr : (m == 1) ? a.Whz : a.Whh;
      srcrow = W + (size_t)(2 * g + ci2) * Hn;
      dst = (m == 0) ? WhrL[ci2] : (m == 1) ? WhzL[ci2] : WhhL[ci2];
    } else {
      const int n2 = n - 384, mat = n2 / 384, rem = n2 % 384;
      const int ci2 = rem / 192, rem2 = rem % 192, gate = rem2 / 64; q = rem2 & 63;
      const float* W = mat ? a.W_hh : a.W_ih;
      srcrow = W + (size_t)(gate * Hn + 2 * g + ci2) * Hn;
      dst = mat ? Wh2L[ci2][gate] : WihL[ci2][gate];
    }
    const float* s8 = srcrow + q * 8;
    uint4 u;
    u.x = pack2(s8[0], s8[1]); u.y = pack2(s8[2], s8[3]);
    u.z = pack2(s8[4], s8[5]); u.w = pack2(s8[6], s8[7]);
    dst[q] = u;
  }
  for (int i = tid; i < Dn * 4 * PREPn; i += NT) wprepL[i] = a.w_prep[i];
  bprepL[tid] = a.bias_prep[tid];                  // exactly 512
  if (tid < PHn)    bp1L[tid] = a.bp1[tid];
  if (tid < 2 * Dn) bp2L[tid] = a.bp2[tid];
  if (tid < CLFHn)  { bclfL[tid] = a.bclf1[tid]; wclf2L[tid] = a.Wclf2[tid]; }
  if (tid < 12) {
    const int ci2 = tid / 6, rem = tid % 6, gate = rem >> 1, s = rem & 1;
    const int j = gate * Hn + 2 * g + ci2;
    bgL[tid] = s ? a.b_hh[j] : a.b_ih[j];
  }
  const float bclf2r = a.bclf2[0];

  // ---- h0 for row g ----
  if (tid < COVn) covL[tid] = a.cov[g * COVn + tid];
  __syncthreads();
  if (tid < COVHn) {
    float acc = a.bc1[tid];
    #pragma unroll
    for (int k = 0; k < COVn; ++k) acc += covL[k] * a.Wc1[tid * COVn + k];
    t1L[tid] = fmaxf(acc, 0.0f);
  }
  __syncthreads();
  {
    float acc = a.bc2[tid];
    for (int k = 0; k < COVHn; ++k) acc += t1L[k] * a.Wc2[tid * COVHn + k];
    const float h0 = tanhf(acc);
    a.hA[qidx(g, tid)] = (_Float16)h0;
    a.hAf[g * Hn + tid] = h0;
  }

  unsigned mygen = 0;
  grid_barrier(a.bar, mygen);

  float hrc = 0.f, zz = 0.f, hbc = 0.f;   // per-thread carries for (r, c)

  for (int t = 0; t < Tn; ++t) {
    // ---- P1: r,z for owned column; rh publish; classifier for t-1 ----
    {
      float sr = 0.f, sz = 0.f;
      #pragma unroll 4
      for (int q = 0; q < Hn / 8; ++q) {
        const uint4 hq = hAQ[q * Bn + r];
        sr = dotq(WhrL[ci][q], hq, sr);
        sz = dotq(WhzL[ci][q], hq, sz);
      }
      hrc = a.hAf[r * Hn + c];
      const float rr = sigmoidf(sr);
      zz = sigmoidf(sz);
      a.rh[qidx(r, c)] = (_Float16)(rr * hrc);
    }
    if (t > 0) do_clf(a, bclfL, wclf2L, bclf2r, g, tid, t - 1);
    grid_barrier(a.bar, mygen);

    // ---- P2: u = tanh(rh@Whh^T); Euler; publish hB ----
    {
      float su = 0.f;
      #pragma unroll 4
      for (int q = 0; q < Hn / 8; ++q)
        su = dotq(WhhL[ci][q], rhQ[q * Bn + r], su);
      const float u = tanhf(su);
      hbc = hrc + DTc * (1.0f - zz) * (u - hrc);
      a.hB[qidx(r, c)] = (_Float16)hbc;
    }
    grid_barrier(a.bar, mygen);

    // ---- P3 (per-row g): q -> p -> prep -> gi, obs ----
    if (tid < 64)        hrowL[tid]      = hBQ[tid * Bn + g];
    else if (tid < 96)   xrowL[tid - 64] = a.X[((size_t)t * Bn + g) * Dn + (tid - 64)];
    else if (tid < 128)  mrowL[tid - 96] = a.M[((size_t)t * Bn + g) * Dn + (tid - 96)];
    __syncthreads();
    if (tid < PHn) {
      float acc = bp1L[tid];
      #pragma unroll 4
      for (int q = 0; q < Hn / 8; ++q)
        acc = dotq(a.Wp1Q[q * PHn + tid], hrowL[q], acc);
      ((_Float16*)qrowL)[tid] = (_Float16)fmaxf(acc, 0.0f);
    }
    __syncthreads();
    if (tid < 2 * Dn) {
      float acc = bp2L[tid];
      #pragma unroll 4
      for (int q = 0; q < PHn / 8; ++q)
        acc = dotq(a.Wp2Q[q * (2 * Dn) + tid], qrowL[q], acc);
      pL[tid] = acc;
    }
    __syncthreads();
    {
      const int d = tid >> 4, pp = tid & 15;
      const float xv   = xrowL[d];
      const float mean = pL[d];
      const float logv = pL[Dn + d];
      const float err  = (xv - mean) * __expf(-0.5f * logv);
      float acc = bprepL[d * PREPn + pp];
      acc += xv   * wprepL[(d * 4 + 0) * PREPn + pp];
      acc += mean * wprepL[(d * 4 + 1) * PREPn + pp];
      acc += logv * wprepL[(d * 4 + 2) * PREPn + pp];
      acc += err  * wprepL[(d * 4 + 3) * PREPn + pp];
      a.gi[qidx(g, tid)] = (_Float16)(fmaxf(acc, 0.0f) * mrowL[d]);
      if (tid == 0) {
        float s = 0.f;
        for (int dd = 0; dd < Dn; ++dd) s += mrowL[dd];
        a.obs[g] = (s > 0.0f) ? 1.0f : 0.0f;
      }
    }
    grid_barrier(a.bar, mygen);

    // ---- P4: GRUCell gates for owned column; masked update; publish hA ----
    {
      float gr  = bgL[ci * 6 + 0] + bgL[ci * 6 + 1];
      float gz  = bgL[ci * 6 + 2] + bgL[ci * 6 + 3];
      float xn  = bgL[ci * 6 + 4];
      float hnb = bgL[ci * 6 + 5];
      #pragma unroll 2
      for (int q = 0; q < Hn / 8; ++q) {
        const uint4 gq = giQ[q * Bn + r];
        const uint4 hq = hBQ[q * Bn + r];
        gr  = dotq(WihL[ci][0][q], gq, gr);  gr  = dotq(Wh2L[ci][0][q], hq, gr);
        gz  = dotq(WihL[ci][1][q], gq, gz);  gz  = dotq(Wh2L[ci][1][q], hq, gz);
        xn  = dotq(WihL[ci][2][q], gq, xn);  hnb = dotq(Wh2L[ci][2][q], hq, hnb);
      }
      const float rg  = sigmoidf(gr);
      const float zgg = sigmoidf(gz);
      const float ng  = tanhf(xn + rg * hnb);
      const float hf  = (a.obs[r] > 0.0f) ? ((1.0f - zgg) * ng + zgg * hbc) : hbc;
      a.hA[qidx(r, c)] = (_Float16)hf;
      a.hAf[r * Hn + c] = hf;
    }
    grid_barrier(a.bar, mygen);
  }

  // ---- final classifier for t = 199 ----
  do_clf(a, bclfL, wclf2L, bclf2r, g, tid, Tn - 1);
}

extern "C" void kernel_launch(void* const* d_in, const int* in_sizes, int n_in,
                              void* d_out, int out_size, void* d_ws, size_t ws_size,
                              hipStream_t stream) {
  char* ws = (char*)d_ws;

  CoopArgs a;
  a.cov  = (const float*)d_in[0];
  a.X    = (const float*)d_in[1];
  a.M    = (const float*)d_in[2];
  a.Wc1  = (const float*)d_in[3];  a.bc1 = (const float*)d_in[4];
  a.Wc2  = (const float*)d_in[5];  a.bc2 = (const float*)d_in[6];
  a.Whr  = (const float*)d_in[7];  a.Whz = (const float*)d_in[8];  a.Whh = (const float*)d_in[9];
  const float* Wp1 = (const float*)d_in[10]; a.bp1 = (const float*)d_in[11];
  const float* Wp2 = (const float*)d_in[12]; a.bp2 = (const float*)d_in[13];
  a.w_prep = (const float*)d_in[14]; a.bias_prep = (const float*)d_in[15];
  a.W_ih = (const float*)d_in[16]; a.W_hh = (const float*)d_in[17];
  a.b_ih = (const float*)d_in[18]; a.b_hh = (const float*)d_in[19];
  const float* Wclf1 = (const float*)d_in[20]; a.bclf1 = (const float*)d_in[21];
  a.Wclf2 = (const float*)d_in[22]; a.bclf2 = (const float*)d_in[23];

  _Float16* pk = (_Float16*)ws;
  a.Wp1Q   = (const uint4*)(pk + PK_WP1);
  a.Wp2Q   = (const uint4*)(pk + PK_WP2);
  a.Wclf1Q = (const uint4*)(pk + PK_WCLF1);
  a.hA  = (_Float16*)(ws + WS_HA);
  a.hB  = (_Float16*)(ws + WS_HB);
  a.rh  = (_Float16*)(ws + WS_RH);
  a.gi  = (_Float16*)(ws + WS_GI);
  a.hAf = (float*)(ws + WS_HAF);
  a.obs = (float*)(ws + WS_OBS);
  a.bar = (unsigned*)(ws + WS_BAR);
  a.out = (float*)d_out;

  PrepArgs p;
  p.Wp1 = Wp1; p.Wp2 = Wp2; p.Wclf1 = Wclf1;
  p.dst = pk; p.bar = a.bar;
  prep_pack_kernel<<<PK_TOTAL / 256, 256, 0, stream>>>(p);
  gruode_coop<<<Bn, NT, 0, stream>>>(a);
}

// Round 4
// 16046.246 us; speedup vs baseline: 1.5969x; 1.5969x over previous
//
#include <hip/hip_runtime.h>
#include <hip/hip_bf16.h>

// Problem constants
constexpr int Bn = 256, Tn = 200, Dn = 32, Hn = 512, PHn = 256, PREPn = 16;
constexpr int COVn = 32, COVHn = 128, CLFHn = 64;
constexpr float DTc = 0.05f;
constexpr int NT = 512;   // threads per block; grid = 256 (block g owns cols {2g,2g+1}, row g)

// Distributed grid barrier: 64 counters, 128B apart (separate cachelines)
constexpr int NCTR = 64, CSTR = 32;   // CSTR in u32s -> 128B stride

typedef _Float16 h2v __attribute__((ext_vector_type(2)));

// packed f16 quad layout for streamed matrices: elem (k,j) of [N,K] at ((k>>3)*N + j)*8 + (k&7)
constexpr int PK_WP1   = 0;        // 256x512
constexpr int PK_WP2   = 131072;   // 64x256
constexpr int PK_WCLF1 = 147456;   // 64x512
constexpr int PK_TOTAL = 180224;

// ws byte offsets
constexpr size_t WS_HA  = 393216;   // f16 [256r x 512k] quad-transposed (256KB)
constexpr size_t WS_HB  = 655360;
constexpr size_t WS_RH  = 917504;
constexpr size_t WS_GI  = 1179648;
constexpr size_t WS_H0F = 1441792;  // f32 [256][512], written once (h0 exchange)
constexpr size_t WS_OBS = 1966080;  // f32 [256]
constexpr size_t WS_BAR = 1967104;  // NCTR*CSTR u32 = 8KB, zeroed by prep kernel

__device__ __forceinline__ float sigmoidf(float x) { return 1.0f / (1.0f + __expf(-x)); }

__device__ __forceinline__ float fdot2(unsigned w, unsigned v, float acc) {
#if __has_builtin(__builtin_amdgcn_fdot2)
  return __builtin_amdgcn_fdot2(__builtin_bit_cast(h2v, w),
                                __builtin_bit_cast(h2v, v), acc, false);
#else
  h2v a = __builtin_bit_cast(h2v, w), b = __builtin_bit_cast(h2v, v);
  return acc + (float)a.x * (float)b.x + (float)a.y * (float)b.y;
#endif
}
__device__ __forceinline__ float dotq(uint4 w, uint4 h, float acc) {
  acc = fdot2(w.x, h.x, acc); acc = fdot2(w.y, h.y, acc);
  acc = fdot2(w.z, h.z, acc); acc = fdot2(w.w, h.w, acc);
  return acc;
}
__device__ __forceinline__ unsigned pack2(float a, float b) {
  h2v h; h.x = (_Float16)a; h.y = (_Float16)b;
  return __builtin_bit_cast(unsigned, h);
}
__device__ __forceinline__ int qidx(int r, int k) { return ((k >> 3) * Bn + r) * 8 + (k & 7); }

__device__ __forceinline__ void fence_rel() {
#if __has_builtin(__builtin_amdgcn_fence)
  __builtin_amdgcn_fence(__ATOMIC_RELEASE, "agent");
#else
  __threadfence();
#endif
}
__device__ __forceinline__ void fence_acq() {
#if __has_builtin(__builtin_amdgcn_fence)
  __builtin_amdgcn_fence(__ATOMIC_ACQUIRE, "agent");
#else
  __threadfence();
#endif
}

// ---- split-phase distributed grid barrier ----
__device__ __forceinline__ void bar_arrive(unsigned* ctrs) {
  __syncthreads();                       // all block stores issued (vmcnt drained)
  if (threadIdx.x == 0) {
    fence_rel();                         // flush XCD L2 -> coherence point
    __hip_atomic_fetch_add(&ctrs[(blockIdx.x & (NCTR - 1)) * CSTR], 1u,
                           __ATOMIC_RELAXED, __HIP_MEMORY_SCOPE_AGENT);
  }
}
__device__ __forceinline__ void bar_wait(unsigned* ctrs, unsigned& ep) {
  ep += 1;
  const unsigned target = ep * (unsigned)Bn;   // monotone arrival total
  if (threadIdx.x < NCTR) {
    unsigned* myc = &ctrs[threadIdx.x * CSTR];
    for (;;) {
      unsigned s = __hip_atomic_load(myc, __ATOMIC_RELAXED, __HIP_MEMORY_SCOPE_AGENT);
      #pragma unroll
      for (int o = 32; o; o >>= 1) s += __shfl_down(s, o, 64);
      s = __shfl(s, 0, 64);
      if (s >= target) break;
      __builtin_amdgcn_s_sleep(4);
    }
    if (threadIdx.x == 0) fence_acq();   // single L2-invalidate per block per barrier
  }
  __syncthreads();
}

// ---------------- prep: pack Wp1/Wp2/Wclf1 to f16 quads; zero barrier counters ----------------
struct PrepArgs { const float *Wp1, *Wp2, *Wclf1; _Float16* dst; unsigned* bar; };

__global__ void prep_pack_kernel(PrepArgs a) {
  const int idx = blockIdx.x * 256 + threadIdx.x;
  if (idx < NCTR * CSTR) a.bar[idx] = 0u;
  if (idx >= PK_TOTAL) return;
  int off, N, K; const float* src;
  if      (idx < PK_WP2)   { off = PK_WP1;   N = 256; K = 512; src = a.Wp1; }
  else if (idx < PK_WCLF1) { off = PK_WP2;   N = 64;  K = 256; src = a.Wp2; }
  else                     { off = PK_WCLF1; N = 64;  K = 512; src = a.Wclf1; }
  const int li = idx - off, e = li & 7, t2 = li >> 3, j = t2 % N, k8 = t2 / N;
  a.dst[idx] = (_Float16)src[(size_t)j * K + k8 * 8 + e];
}

// ---------------- main persistent kernel ----------------
struct CoopArgs {
  const float *cov, *X, *M;
  const float *Wc1, *bc1, *Wc2, *bc2;
  const float *Whr, *Whz, *Whh;
  const float *bp1, *bp2;
  const float *w_prep, *bias_prep;
  const float *W_ih, *W_hh, *b_ih, *b_hh;
  const float *bclf1, *Wclf2, *bclf2;
  const uint4 *Wp1Q, *Wp2Q, *Wclf1Q;
  _Float16 *hA, *hB, *rh, *gi;
  float *h0f, *obs;
  unsigned* bar;
  float* out;
};

__device__ __forceinline__ void do_clf(const CoopArgs& a, const float* bclfL,
                                       const float* wclf2L, float bclf2r,
                                       int g, int tid, int tout) {
  if (tid < CLFHn) {
    const uint4* hAQ = (const uint4*)a.hA;
    float acc = bclfL[tid];
    #pragma unroll 4
    for (int q = 0; q < Hn / 8; ++q)
      acc = dotq(a.Wclf1Q[q * CLFHn + tid], hAQ[q * Bn + g], acc);
    float cc = fmaxf(acc, 0.0f) * wclf2L[tid];
    #pragma unroll
    for (int off = 32; off; off >>= 1) cc += __shfl_down(cc, off, 64);
    if (tid == 0) a.out[tout * Bn + g] = cc + bclf2r;
  }
}

__global__ __launch_bounds__(NT)
void gruode_coop(CoopArgs a) {
  const int g   = blockIdx.x;
  const int tid = threadIdx.x;
  const int ci  = tid >> 8;      // which of the 2 owned columns
  const int r   = tid & 255;     // batch row for column-phases
  const int c   = 2 * g + ci;    // owned H column

  __shared__ __align__(16) uint4 WhrL[2][64], WhzL[2][64], WhhL[2][64];   // 6 KB
  __shared__ __align__(16) uint4 WihL[2][3][64], Wh2L[2][3][64];          // 12 KB
  __shared__ __align__(16) uint4 hrowL[64];
  __shared__ __align__(16) uint4 qrowL[32];
  __shared__ float pL[2 * Dn];
  __shared__ float xrowL[Dn], mrowL[Dn];
  __shared__ float wprepL[Dn * 4 * PREPn];
  __shared__ float bprepL[Dn * PREPn];
  __shared__ float bp1L[PHn], bp2L[2 * Dn];
  __shared__ float bclfL[CLFHn], wclf2L[CLFHn];
  __shared__ float bgL[12];
  __shared__ float t1L[COVHn], covL[COVn];

  const uint4* hAQ = (const uint4*)a.hA;
  const uint4* hBQ = (const uint4*)a.hB;
  const uint4* rhQ = (const uint4*)a.rh;
  const uint4* giQ = (const uint4*)a.gi;

  // ---- one-time init: stage owned weight slices f32 -> f16 quads in LDS ----
  for (int n = tid; n < 1152; n += NT) {
    const float* srcrow; uint4* dst; int q;
    if (n < 384) {
      const int m = n >> 7, rem = n & 127, ci2 = rem >> 6; q = rem & 63;
      const float* W = (m == 0) ? a.Whr : (m == 1) ? a.Whz : a.Whh;
      srcrow = W + (size_t)(2 * g + ci2) * Hn;
      dst = (m == 0) ? WhrL[ci2] : (m == 1) ? WhzL[ci2] : WhhL[ci2];
    } else {
      const int n2 = n - 384, mat = n2 / 384, rem = n2 % 384;
      const int ci2 = rem / 192, rem2 = rem % 192, gate = rem2 / 64; q = rem2 & 63;
      const float* W = mat ? a.W_hh : a.W_ih;
      srcrow = W + (size_t)(gate * Hn + 2 * g + ci2) * Hn;
      dst = mat ? Wh2L[ci2][gate] : WihL[ci2][gate];
    }
    const float* s8 = srcrow + q * 8;
    uint4 u;
    u.x = pack2(s8[0], s8[1]); u.y = pack2(s8[2], s8[3]);
    u.z = pack2(s8[4], s8[5]); u.w = pack2(s8[6], s8[7]);
    dst[q] = u;
  }
  for (int i = tid; i < Dn * 4 * PREPn; i += NT) wprepL[i] = a.w_prep[i];
  bprepL[tid] = a.bias_prep[tid];
  if (tid < PHn)    bp1L[tid] = a.bp1[tid];
  if (tid < 2 * Dn) bp2L[tid] = a.bp2[tid];
  if (tid < CLFHn)  { bclfL[tid] = a.bclf1[tid]; wclf2L[tid] = a.Wclf2[tid]; }
  if (tid < 12) {
    const int ci2 = tid / 6, rem = tid % 6, gate = rem >> 1, s = rem & 1;
    const int j = gate * Hn + 2 * g + ci2;
    bgL[tid] = s ? a.b_hh[j] : a.b_ih[j];
  }
  const float bclf2r = a.bclf2[0];

  // ---- h0 for row g; publish f16 quads + f32 once ----
  if (tid < COVn) covL[tid] = a.cov[g * COVn + tid];
  __syncthreads();
  if (tid < COVHn) {
    float acc = a.bc1[tid];
    #pragma unroll
    for (int k = 0; k < COVn; ++k) acc += covL[k] * a.Wc1[tid * COVn + k];
    t1L[tid] = fmaxf(acc, 0.0f);
  }
  __syncthreads();
  {
    float acc = a.bc2[tid];
    for (int k = 0; k < COVHn; ++k) acc += t1L[k] * a.Wc2[tid * COVHn + k];
    const float h0 = tanhf(acc);
    a.hA[qidx(g, tid)] = (_Float16)h0;
    a.h0f[g * Hn + tid] = h0;
  }

  unsigned ep = 0;
  bar_arrive(a.bar);
  bar_wait(a.bar, ep);

  float hfull = a.h0f[(size_t)r * Hn + c];   // thread-owned f32 h[r,c], lives in reg forever
  float zz = 0.f, hbc = 0.f;

  for (int t = 0; t < Tn; ++t) {
    // ---- P1: r,z for owned column; publish rh ----
    {
      float sr = 0.f, sz = 0.f;
      #pragma unroll 8
      for (int q = 0; q < Hn / 8; ++q) {
        const uint4 hq = hAQ[q * Bn + r];
        sr = dotq(WhrL[ci][q], hq, sr);
        sz = dotq(WhzL[ci][q], hq, sz);
      }
      const float rr = sigmoidf(sr);
      zz = sigmoidf(sz);
      a.rh[qidx(r, c)] = (_Float16)(rr * hfull);
    }
    bar_arrive(a.bar);
    if (t > 0) do_clf(a, bclfL, wclf2L, bclf2r, g, tid, t - 1);  // hides B1 wait
    bar_wait(a.bar, ep);

    // ---- P2: u = tanh(rh@Whh^T); Euler; publish hB ----
    {
      float su = 0.f;
      #pragma unroll 8
      for (int q = 0; q < Hn / 8; ++q)
        su = dotq(WhhL[ci][q], rhQ[q * Bn + r], su);
      const float u = tanhf(su);
      hbc = hfull + DTc * (1.0f - zz) * (u - hfull);
      a.hB[qidx(r, c)] = (_Float16)hbc;
    }
    bar_arrive(a.bar);
    if (tid >= 64 && tid < 96)        xrowL[tid - 64] = a.X[((size_t)t * Bn + g) * Dn + (tid - 64)];
    else if (tid >= 96 && tid < 128)  mrowL[tid - 96] = a.M[((size_t)t * Bn + g) * Dn + (tid - 96)];
    bar_wait(a.bar, ep);

    // ---- P3 (per-row g): q -> p -> prep -> gi, obs ----
    if (tid < 64) hrowL[tid] = hBQ[tid * Bn + g];
    __syncthreads();
    if (tid < PHn) {
      float acc = bp1L[tid];
      #pragma unroll 8
      for (int q = 0; q < Hn / 8; ++q)
        acc = dotq(a.Wp1Q[q * PHn + tid], hrowL[q], acc);
      ((_Float16*)qrowL)[tid] = (_Float16)fmaxf(acc, 0.0f);
    }
    __syncthreads();
    if (tid < 2 * Dn) {
      float acc = bp2L[tid];
      #pragma unroll 4
      for (int q = 0; q < PHn / 8; ++q)
        acc = dotq(a.Wp2Q[q * (2 * Dn) + tid], qrowL[q], acc);
      pL[tid] = acc;
    }
    __syncthreads();
    {
      const int d = tid >> 4, pp = tid & 15;
      const float xv   = xrowL[d];
      const float mean = pL[d];
      const float logv = pL[Dn + d];
      const float err  = (xv - mean) * __expf(-0.5f * logv);
      float acc = bprepL[d * PREPn + pp];
      acc += xv   * wprepL[(d * 4 + 0) * PREPn + pp];
      acc += mean * wprepL[(d * 4 + 1) * PREPn + pp];
      acc += logv * wprepL[(d * 4 + 2) * PREPn + pp];
      acc += err  * wprepL[(d * 4 + 3) * PREPn + pp];
      a.gi[qidx(g, tid)] = (_Float16)(fmaxf(acc, 0.0f) * mrowL[d]);
      if (tid < 32) {
        unsigned long long bb = __ballot(mrowL[tid] > 0.0f);
        if (tid == 0) a.obs[g] = bb ? 1.0f : 0.0f;
      }
    }
    bar_arrive(a.bar);
    bar_wait(a.bar, ep);

    // ---- P4: GRUCell gates for owned column; masked update; publish hA ----
    {
      float gr  = bgL[ci * 6 + 0] + bgL[ci * 6 + 1];
      float gz  = bgL[ci * 6 + 2] + bgL[ci * 6 + 3];
      float xn  = bgL[ci * 6 + 4];
      float hnb = bgL[ci * 6 + 5];
      #pragma unroll 4
      for (int q = 0; q < Hn / 8; ++q) {
        const uint4 gq = giQ[q * Bn + r];
        const uint4 hq = hBQ[q * Bn + r];
        gr  = dotq(WihL[ci][0][q], gq, gr);  gr  = dotq(Wh2L[ci][0][q], hq, gr);
        gz  = dotq(WihL[ci][1][q], gq, gz);  gz  = dotq(Wh2L[ci][1][q], hq, gz);
        xn  = dotq(WihL[ci][2][q], gq, xn);  hnb = dotq(Wh2L[ci][2][q], hq, hnb);
      }
      const float rg  = sigmoidf(gr);
      const float zgg = sigmoidf(gz);
      const float ng  = tanhf(xn + rg * hnb);
      hfull = (a.obs[r] > 0.0f) ? ((1.0f - zgg) * ng + zgg * hbc) : hbc;
      a.hA[qidx(r, c)] = (_Float16)hfull;
    }
    bar_arrive(a.bar);
    bar_wait(a.bar, ep);
  }

  do_clf(a, bclfL, wclf2L, bclf2r, g, tid, Tn - 1);
}

extern "C" void kernel_launch(void* const* d_in, const int* in_sizes, int n_in,
                              void* d_out, int out_size, void* d_ws, size_t ws_size,
                              hipStream_t stream) {
  char* ws = (char*)d_ws;

  CoopArgs a;
  a.cov  = (const float*)d_in[0];
  a.X    = (const float*)d_in[1];
  a.M    = (const float*)d_in[2];
  a.Wc1  = (const float*)d_in[3];  a.bc1 = (const float*)d_in[4];
  a.Wc2  = (const float*)d_in[5];  a.bc2 = (const float*)d_in[6];
  a.Whr  = (const float*)d_in[7];  a.Whz = (const float*)d_in[8];  a.Whh = (const float*)d_in[9];
  const float* Wp1 = (const float*)d_in[10]; a.bp1 = (const float*)d_in[11];
  const float* Wp2 = (const float*)d_in[12]; a.bp2 = (const float*)d_in[13];
  a.w_prep = (const float*)d_in[14]; a.bias_prep = (const float*)d_in[15];
  a.W_ih = (const float*)d_in[16]; a.W_hh = (const float*)d_in[17];
  a.b_ih = (const float*)d_in[18]; a.b_hh = (const float*)d_in[19];
  const float* Wclf1 = (const float*)d_in[20]; a.bclf1 = (const float*)d_in[21];
  a.Wclf2 = (const float*)d_in[22]; a.bclf2 = (const float*)d_in[23];

  _Float16* pk = (_Float16*)ws;
  a.Wp1Q   = (const uint4*)(pk + PK_WP1);
  a.Wp2Q   = (const uint4*)(pk + PK_WP2);
  a.Wclf1Q = (const uint4*)(pk + PK_WCLF1);
  a.hA  = (_Float16*)(ws + WS_HA);
  a.hB  = (_Float16*)(ws + WS_HB);
  a.rh  = (_Float16*)(ws + WS_RH);
  a.gi  = (_Float16*)(ws + WS_GI);
  a.h0f = (float*)(ws + WS_H0F);
  a.obs = (float*)(ws + WS_OBS);
  a.bar = (unsigned*)(ws + WS_BAR);
  a.out = (float*)d_out;

  PrepArgs p;
  p.Wp1 = Wp1; p.Wp2 = Wp2; p.Wclf1 = Wclf1;
  p.dst = pk; p.bar = a.bar;
  prep_pack_kernel<<<PK_TOTAL / 256, 256, 0, stream>>>(p);
  gruode_coop<<<Bn, NT, 0, stream>>>(a);
}

// Round 5
// 9793.491 us; speedup vs baseline: 2.6164x; 1.6385x over previous
//
#include <hip/hip_runtime.h>
#include <hip/hip_bf16.h>

// Problem constants
constexpr int Bn = 256, Tn = 200, Dn = 32, Hn = 512, PHn = 256, PREPn = 16;
constexpr int COVn = 32, COVHn = 128, CLFHn = 64;
constexpr float DTc = 0.05f;
constexpr int NT = 512;
// grid = 256 blocks = 64 col-groups x 4 row-groups.
// block (cg,rg): owns H-cols [8cg,8cg+8) x batch-rows [64rg,64rg+64); also row-duty g=bid for P3/clf.

constexpr int NCTR = 64, CSTR = 32;   // distributed barrier: 64 counters, 128B apart

typedef _Float16 h2v __attribute__((ext_vector_type(2)));

// packed f16 quad layout for streamed matrices: elem (k,j) of [N,K] at ((k>>3)*N + j)*8 + (k&7)
constexpr int PK_WP1   = 0;        // 256x512
constexpr int PK_WP2   = 131072;   // 64x256
constexpr int PK_WCLF1 = 147456;   // 64x512
constexpr int PK_TOTAL = 180224;

// ws byte offsets
constexpr size_t WS_HA  = 393216;   // f16 [quad k8][256 rows][8] (256KB)
constexpr size_t WS_HB  = 655360;
constexpr size_t WS_RH  = 917504;
constexpr size_t WS_GI  = 1179648;
constexpr size_t WS_H0F = 1441792;  // f32 [256][512] one-time h0 exchange
constexpr size_t WS_OBS = 1966080;  // f32 [256]
constexpr size_t WS_BAR = 1967104;  // NCTR*CSTR u32, zeroed by prep kernel

__device__ __forceinline__ float sigmoidf(float x) { return 1.0f / (1.0f + __expf(-x)); }

__device__ __forceinline__ float fdot2(unsigned w, unsigned v, float acc) {
#if __has_builtin(__builtin_amdgcn_fdot2)
  return __builtin_amdgcn_fdot2(__builtin_bit_cast(h2v, w),
                                __builtin_bit_cast(h2v, v), acc, false);
#else
  h2v a = __builtin_bit_cast(h2v, w), b = __builtin_bit_cast(h2v, v);
  return acc + (float)a.x * (float)b.x + (float)a.y * (float)b.y;
#endif
}
__device__ __forceinline__ float dotq(uint4 w, uint4 h, float acc) {
  acc = fdot2(w.x, h.x, acc); acc = fdot2(w.y, h.y, acc);
  acc = fdot2(w.z, h.z, acc); acc = fdot2(w.w, h.w, acc);
  return acc;
}
__device__ __forceinline__ unsigned pack2(float a, float b) {
  h2v h; h.x = (_Float16)a; h.y = (_Float16)b;
  return __builtin_bit_cast(unsigned, h);
}

// L2-bypassing (coherent) accesses for cross-block activation data
__device__ __forceinline__ unsigned long long cohL(const unsigned long long* p) {
  return __hip_atomic_load(p, __ATOMIC_RELAXED, __HIP_MEMORY_SCOPE_SYSTEM);
}
__device__ __forceinline__ void cohS(unsigned long long* p, unsigned long long v) {
  __hip_atomic_store(p, v, __ATOMIC_RELAXED, __HIP_MEMORY_SCOPE_SYSTEM);
}
__device__ __forceinline__ float cohLf(const float* p) {
  return __hip_atomic_load(p, __ATOMIC_RELAXED, __HIP_MEMORY_SCOPE_SYSTEM);
}
__device__ __forceinline__ void cohSf(float* p, float v) {
  __hip_atomic_store(p, v, __ATOMIC_RELAXED, __HIP_MEMORY_SCOPE_SYSTEM);
}

// ---- fence-free distributed grid barrier (coherence via L2-bypass data ops) ----
__device__ __forceinline__ void bar_arrive(unsigned* ctrs) {
  __syncthreads();   // drains vmcnt: all coherent stores reached L3 before counter bump
  if (threadIdx.x == 0)
    __hip_atomic_fetch_add(&ctrs[(blockIdx.x & (NCTR - 1)) * CSTR], 1u,
                           __ATOMIC_RELAXED, __HIP_MEMORY_SCOPE_AGENT);
}
__device__ __forceinline__ void bar_wait(unsigned* ctrs, unsigned& ep) {
  ep += 1;
  const unsigned target = ep * (unsigned)Bn;
  if (threadIdx.x < NCTR) {
    const unsigned* myc = &ctrs[threadIdx.x * CSTR];
    for (;;) {
      unsigned s = __hip_atomic_load(myc, __ATOMIC_RELAXED, __HIP_MEMORY_SCOPE_AGENT);
      #pragma unroll
      for (int o = 32; o; o >>= 1) s += __shfl_down(s, o, 64);
      s = __shfl(s, 0, 64);
      if (s >= target) break;
      __builtin_amdgcn_s_sleep(2);
    }
  }
  __syncthreads();
}

// ---------------- prep: pack Wp1/Wp2/Wclf1 to f16 quads; zero barrier counters ----------------
struct PrepArgs { const float *Wp1, *Wp2, *Wclf1; _Float16* dst; unsigned* bar; };

__global__ void prep_pack_kernel(PrepArgs a) {
  const int idx = blockIdx.x * 256 + threadIdx.x;
  if (idx < NCTR * CSTR) a.bar[idx] = 0u;
  if (idx >= PK_TOTAL) return;
  int off, N, K; const float* src;
  if      (idx < PK_WP2)   { off = PK_WP1;   N = 256; K = 512; src = a.Wp1; }
  else if (idx < PK_WCLF1) { off = PK_WP2;   N = 64;  K = 256; src = a.Wp2; }
  else                     { off = PK_WCLF1; N = 64;  K = 512; src = a.Wclf1; }
  const int li = idx - off, e = li & 7, t2 = li >> 3, j = t2 % N, k8 = t2 / N;
  a.dst[idx] = (_Float16)src[(size_t)j * K + k8 * 8 + e];
}

// ---------------- main persistent kernel ----------------
struct CoopArgs {
  const float *cov, *X, *M;
  const float *Wc1, *bc1, *Wc2, *bc2;
  const float *Whr, *Whz, *Whh;
  const float *bp1, *bp2;
  const float *w_prep, *bias_prep;
  const float *W_ih, *W_hh, *b_ih, *b_hh;
  const float *bclf1, *Wclf2, *bclf2;
  const uint4 *Wp1Q, *Wp2Q, *Wclf1Q;
  unsigned long long *hA, *hB, *rh, *gi;   // u64 views of f16 arrays
  float *h0f, *obs;
  unsigned* bar;
  float* out;
};

__global__ __launch_bounds__(NT)
void gruode_coop(CoopArgs a) {
  const int bid = blockIdx.x, tid = threadIdx.x;
  const int cg = bid >> 2, rg = bid & 3, g = bid;
  const int c_loc = tid >> 6, r_loc = tid & 63;
  const int c = cg * 8 + c_loc, r = rg * 64 + r_loc;

  // LDS-resident weight slices for the 8 owned columns (~72KB)
  __shared__ __align__(16) uint4 WabL[3][8][64];      // Whr/Whz/Whh rows
  __shared__ __align__(16) uint4 WgL[2][3][8][64];    // W_ih/W_hh gate rows
  __shared__ __align__(16) uint4 stageQ[64 * 64];     // [quad][row] staged activations, 64KB
  __shared__ __align__(16) uint4 hrowQ[64];
  __shared__ __align__(16) uint4 qrowQ[32];
  __shared__ __align__(8)  _Float16 outH[512];
  __shared__ __align__(8)  _Float16 giH[512];
  __shared__ float h0L[512];
  __shared__ float wprepL[Dn * 4 * PREPn];
  __shared__ float bprepL[Dn * PREPn];
  __shared__ float bp1L[PHn], bp2L[2 * Dn], pL[2 * Dn];
  __shared__ float xrowL[Dn], mrowL[Dn];
  __shared__ float bclfL[CLFHn], wclf2L[CLFHn], bgL[48];
  __shared__ float covL[COVn], t1L[COVHn];
  __shared__ float obsL[64];

  unsigned long long* stageU = (unsigned long long*)stageQ;
  unsigned long long* outU   = (unsigned long long*)outH;
  unsigned long long* giU    = (unsigned long long*)giH;
  unsigned long long* hrowU  = (unsigned long long*)hrowQ;

  // ---- one-time: stage owned weight slices f32 -> f16 quads in LDS ----
  for (int n = tid; n < 4608; n += NT) {
    const float* srow; uint4* dst; int q;
    if (n < 1536) {
      const int m = n >> 9, rem = n & 511, cl = rem >> 6; q = rem & 63;
      const float* W = (m == 0) ? a.Whr : (m == 1) ? a.Whz : a.Whh;
      srow = W + (size_t)(cg * 8 + cl) * Hn;
      dst = &WabL[m][cl][0];
    } else {
      const int n2 = n - 1536;
      const int mat = n2 / 1536, rem = n2 % 1536, gate = rem / 512, w2 = rem % 512;
      const int cl = w2 >> 6; q = w2 & 63;
      const float* W = mat ? a.W_hh : a.W_ih;
      srow = W + (size_t)(gate * Hn + cg * 8 + cl) * Hn;
      dst = &WgL[mat][gate][cl][0];
    }
    const float* s8 = srow + q * 8;
    uint4 u;
    u.x = pack2(s8[0], s8[1]); u.y = pack2(s8[2], s8[3]);
    u.z = pack2(s8[4], s8[5]); u.w = pack2(s8[6], s8[7]);
    dst[q] = u;
  }
  for (int i = tid; i < Dn * 4 * PREPn; i += NT) wprepL[i] = a.w_prep[i];
  bprepL[tid & 511] = a.bias_prep[tid & 511];
  if (tid < PHn)    bp1L[tid] = a.bp1[tid];
  if (tid < 2 * Dn) bp2L[tid] = a.bp2[tid];
  if (tid < CLFHn)  { bclfL[tid] = a.bclf1[tid]; wclf2L[tid] = a.Wclf2[tid]; }
  if (tid < 48) {
    const int cl = tid / 6, rem = tid % 6, gate = rem >> 1, s = rem & 1;
    const int j = gate * Hn + cg * 8 + cl;
    bgL[tid] = s ? a.b_hh[j] : a.b_ih[j];
  }
  const float bclf2r = a.bclf2[0];

  // ---- h0 for duty-row g ----
  if (tid < COVn) covL[tid] = a.cov[g * COVn + tid];
  __syncthreads();
  if (tid < COVHn) {
    float acc = a.bc1[tid];
    #pragma unroll
    for (int k = 0; k < COVn; ++k) acc += covL[k] * a.Wc1[tid * COVn + k];
    t1L[tid] = fmaxf(acc, 0.0f);
  }
  __syncthreads();
  {
    float acc = a.bc2[tid];
    for (int k = 0; k < COVHn; ++k) acc += t1L[k] * a.Wc2[tid * COVHn + k];
    h0L[tid] = tanhf(acc);
  }
  __syncthreads();
  // publish hA row g (f16, coherent) + h0f row g (f32, coherent)
  if (tid < 128) {
    const int k8 = tid >> 1, half = tid & 1, base = k8 * 8 + half * 4;
    const unsigned lo = pack2(h0L[base], h0L[base + 1]);
    const unsigned hi = pack2(h0L[base + 2], h0L[base + 3]);
    cohS(&a.hA[(size_t)k8 * 512 + g * 2 + half],
         ((unsigned long long)hi << 32) | lo);
  }
  cohSf(&a.h0f[(size_t)g * Hn + tid], h0L[tid]);

  unsigned ep = 0;
  bar_arrive(a.bar); bar_wait(a.bar, ep);

  float hfull = cohLf(&a.h0f[(size_t)r * Hn + c]);   // thread-owned f32 h[r,c]
  float zz = 0.f, hbc = 0.f;

  const size_t oub = (size_t)(cg * 256 + rg * 64) * 2;   // u64 base of block's output region

  // stage 64 owned rows of a [quad][256 rows][8] f16 array into stageQ
  auto stage_fill = [&](const unsigned long long* A) {
    #pragma unroll
    for (int i = 0; i < 16; ++i) {
      const int idx = tid + i * NT;              // 0..8191
      const int q = idx >> 7, lane7 = idx & 127;
      stageU[idx] = cohL(&A[(size_t)q * 512 + rg * 128 + lane7]);
    }
  };
  auto do_clf = [&](int tout) {
    if (tid < 128) hrowU[tid] = cohL(&a.hA[(size_t)(tid >> 1) * 512 + g * 2 + (tid & 1)]);
    __syncthreads();
    if (tid < CLFHn) {
      float acc = bclfL[tid];
      #pragma unroll 8
      for (int q = 0; q < Hn / 8; ++q) acc = dotq(a.Wclf1Q[q * CLFHn + tid], hrowQ[q], acc);
      float cc = fmaxf(acc, 0.0f) * wclf2L[tid];
      #pragma unroll
      for (int o = 32; o; o >>= 1) cc += __shfl_down(cc, o, 64);
      if (tid == 0) a.out[tout * Bn + g] = cc + bclf2r;
    }
  };

  for (int t = 0; t < Tn; ++t) {
    // ---- P1: r,z for owned (r,c); publish rh ----
    stage_fill(a.hA);
    __syncthreads();
    {
      float sr = 0.f, sz = 0.f;
      #pragma unroll 8
      for (int q = 0; q < 64; ++q) {
        const uint4 hq = stageQ[q * 64 + r_loc];
        sr = dotq(WabL[0][c_loc][q], hq, sr);
        sz = dotq(WabL[1][c_loc][q], hq, sz);
      }
      const float rr = sigmoidf(sr);
      zz = sigmoidf(sz);
      outH[r_loc * 8 + c_loc] = (_Float16)(rr * hfull);
    }
    __syncthreads();
    if (tid < 128) cohS(&a.rh[oub + tid], outU[tid]);
    bar_arrive(a.bar);
    if (t > 0) do_clf(t - 1);          // hides barrier wait
    bar_wait(a.bar, ep);

    // ---- P2: u = tanh(rh@Whh^T); Euler; publish hB ----
    stage_fill(a.rh);
    __syncthreads();
    {
      float su = 0.f;
      #pragma unroll 8
      for (int q = 0; q < 64; ++q)
        su = dotq(WabL[2][c_loc][q], stageQ[q * 64 + r_loc], su);
      const float u = tanhf(su);
      hbc = hfull + DTc * (1.0f - zz) * (u - hfull);
      outH[r_loc * 8 + c_loc] = (_Float16)hbc;
    }
    __syncthreads();
    if (tid < 128) cohS(&a.hB[oub + tid], outU[tid]);
    bar_arrive(a.bar);
    if (tid >= 64 && tid < 96)        xrowL[tid - 64] = a.X[((size_t)t * Bn + g) * Dn + (tid - 64)];
    else if (tid >= 96 && tid < 128)  mrowL[tid - 96] = a.M[((size_t)t * Bn + g) * Dn + (tid - 96)];
    bar_wait(a.bar, ep);

    // ---- P3 (duty-row g): q -> p -> prep -> gi, obs ----
    if (tid < 128) hrowU[tid] = cohL(&a.hB[(size_t)(tid >> 1) * 512 + g * 2 + (tid & 1)]);
    __syncthreads();
    if (tid < PHn) {
      float acc = bp1L[tid];
      #pragma unroll 8
      for (int q = 0; q < Hn / 8; ++q)
        acc = dotq(a.Wp1Q[q * PHn + tid], hrowQ[q], acc);
      ((_Float16*)qrowQ)[tid] = (_Float16)fmaxf(acc, 0.0f);
    }
    __syncthreads();
    if (tid < 2 * Dn) {
      float acc = bp2L[tid];
      #pragma unroll 4
      for (int q = 0; q < PHn / 8; ++q)
        acc = dotq(a.Wp2Q[q * (2 * Dn) + tid], qrowQ[q], acc);
      pL[tid] = acc;
    }
    __syncthreads();
    {
      const int d = tid >> 4, pp = tid & 15;
      const float xv   = xrowL[d];
      const float mean = pL[d];
      const float logv = pL[Dn + d];
      const float err  = (xv - mean) * __expf(-0.5f * logv);
      float acc = bprepL[d * PREPn + pp];
      acc += xv   * wprepL[(d * 4 + 0) * PREPn + pp];
      acc += mean * wprepL[(d * 4 + 1) * PREPn + pp];
      acc += logv * wprepL[(d * 4 + 2) * PREPn + pp];
      acc += err  * wprepL[(d * 4 + 3) * PREPn + pp];
      giH[tid] = (_Float16)(fmaxf(acc, 0.0f) * mrowL[d]);
      if (tid < 32) {
        const unsigned long long bb = __ballot(mrowL[tid] > 0.0f);
        if (tid == 0) cohSf(&a.obs[g], bb ? 1.0f : 0.0f);
      }
    }
    __syncthreads();
    if (tid < 128) cohS(&a.gi[(size_t)(tid >> 1) * 512 + g * 2 + (tid & 1)], giU[tid]);
    bar_arrive(a.bar);
    bar_wait(a.bar, ep);

    // ---- P4: GRUCell gates for owned (r,c); masked update; publish hA ----
    stage_fill(a.gi);
    if (tid < 64) obsL[tid] = cohLf(&a.obs[rg * 64 + tid]);
    __syncthreads();
    float gr  = bgL[c_loc * 6 + 0] + bgL[c_loc * 6 + 1];
    float gz  = bgL[c_loc * 6 + 2] + bgL[c_loc * 6 + 3];
    float xn  = bgL[c_loc * 6 + 4];
    float hnb = bgL[c_loc * 6 + 5];
    #pragma unroll 4
    for (int q = 0; q < 64; ++q) {
      const uint4 gq = stageQ[q * 64 + r_loc];
      gr = dotq(WgL[0][0][c_loc][q], gq, gr);
      gz = dotq(WgL[0][1][c_loc][q], gq, gz);
      xn = dotq(WgL[0][2][c_loc][q], gq, xn);
    }
    __syncthreads();
    stage_fill(a.hB);
    __syncthreads();
    #pragma unroll 4
    for (int q = 0; q < 64; ++q) {
      const uint4 hq = stageQ[q * 64 + r_loc];
      gr  = dotq(WgL[1][0][c_loc][q], hq, gr);
      gz  = dotq(WgL[1][1][c_loc][q], hq, gz);
      hnb = dotq(WgL[1][2][c_loc][q], hq, hnb);
    }
    {
      const float rgg = sigmoidf(gr);
      const float zgg = sigmoidf(gz);
      const float ng  = tanhf(xn + rgg * hnb);
      hfull = (obsL[r_loc] > 0.0f) ? ((1.0f - zgg) * ng + zgg * hbc) : hbc;
      outH[r_loc * 8 + c_loc] = (_Float16)hfull;
    }
    __syncthreads();
    if (tid < 128) cohS(&a.hA[oub + tid], outU[tid]);
    bar_arrive(a.bar);
    bar_wait(a.bar, ep);
  }

  do_clf(Tn - 1);
}

extern "C" void kernel_launch(void* const* d_in, const int* in_sizes, int n_in,
                              void* d_out, int out_size, void* d_ws, size_t ws_size,
                              hipStream_t stream) {
  char* ws = (char*)d_ws;

  CoopArgs a;
  a.cov  = (const float*)d_in[0];
  a.X    = (const float*)d_in[1];
  a.M    = (const float*)d_in[2];
  a.Wc1  = (const float*)d_in[3];  a.bc1 = (const float*)d_in[4];
  a.Wc2  = (const float*)d_in[5];  a.bc2 = (const float*)d_in[6];
  a.Whr  = (const float*)d_in[7];  a.Whz = (const float*)d_in[8];  a.Whh = (const float*)d_in[9];
  const float* Wp1 = (const float*)d_in[10]; a.bp1 = (const float*)d_in[11];
  const float* Wp2 = (const float*)d_in[12]; a.bp2 = (const float*)d_in[13];
  a.w_prep = (const float*)d_in[14]; a.bias_prep = (const float*)d_in[15];
  a.W_ih = (const float*)d_in[16]; a.W_hh = (const float*)d_in[17];
  a.b_ih = (const float*)d_in[18]; a.b_hh = (const float*)d_in[19];
  const float* Wclf1 = (const float*)d_in[20]; a.bclf1 = (const float*)d_in[21];
  a.Wclf2 = (const float*)d_in[22]; a.bclf2 = (const float*)d_in[23];

  _Float16* pk = (_Float16*)ws;
  a.Wp1Q   = (const uint4*)(pk + PK_WP1);
  a.Wp2Q   = (const uint4*)(pk + PK_WP2);
  a.Wclf1Q = (const uint4*)(pk + PK_WCLF1);
  a.hA  = (unsigned long long*)(ws + WS_HA);
  a.hB  = (unsigned long long*)(ws + WS_HB);
  a.rh  = (unsigned long long*)(ws + WS_RH);
  a.gi  = (unsigned long long*)(ws + WS_GI);
  a.h0f = (float*)(ws + WS_H0F);
  a.obs = (float*)(ws + WS_OBS);
  a.bar = (unsigned*)(ws + WS_BAR);
  a.out = (float*)d_out;

  PrepArgs p;
  p.Wp1 = Wp1; p.Wp2 = Wp2; p.Wclf1 = Wclf1;
  p.dst = pk; p.bar = a.bar;
  prep_pack_kernel<<<(PK_TOTAL + 255) / 256, 256, 0, stream>>>(p);
  gruode_coop<<<Bn, NT, 0, stream>>>(a);
}

// Round 6
// 9548.311 us; speedup vs baseline: 2.6836x; 1.0257x over previous
//
#include <hip/hip_runtime.h>
#include <hip/hip_bf16.h>

// Problem constants
constexpr int Bn = 256, Tn = 200, Dn = 32, Hn = 512, PHn = 256, PREPn = 16;
constexpr int COVn = 32, COVHn = 128, CLFHn = 64;
constexpr float DTc = 0.05f;
constexpr int NT = 512;
// grid = 256 blocks = 64 col-groups x 4 row-groups (rg = bid&3 -> cohort on 2 XCDs).
// block (cg,rg): owns H-cols [8cg,8cg+8) x batch-rows [64rg,64rg+64); duty row g = rg*64+cg.
// The 4 rg-cohorts are fully independent: barriers are 64-block cohort barriers.

constexpr int CSTR = 32;               // counter line stride in u32 (128B)
constexpr int NLINES = 64;             // 4 cohorts x 16 lines

typedef _Float16 h2v __attribute__((ext_vector_type(2)));

// packed f16 quad layout for streamed matrices: elem (k,j) of [N,K] at ((k>>3)*N + j)*8 + (k&7)
constexpr int PK_WP1   = 0;        // 256x512
constexpr int PK_WP2   = 131072;   // 64x256
constexpr int PK_WCLF1 = 147456;   // 64x512
constexpr int PK_TOTAL = 180224;

// ws byte offsets
constexpr size_t WS_HA  = 393216;   // f16 [quad k8][256 rows][8] (256KB)
constexpr size_t WS_HB  = 655360;
constexpr size_t WS_RH  = 917504;
constexpr size_t WS_GI  = 1179648;
constexpr size_t WS_H0F = 1441792;  // f32 [256][512] one-time h0 exchange
constexpr size_t WS_OBS = 1966080;  // f32 [256]
constexpr size_t WS_BAR = 1967104;  // NLINES*CSTR u32, zeroed by prep kernel

__device__ __forceinline__ float sigmoidf(float x) { return 1.0f / (1.0f + __expf(-x)); }

__device__ __forceinline__ float fdot2(unsigned w, unsigned v, float acc) {
#if __has_builtin(__builtin_amdgcn_fdot2)
  return __builtin_amdgcn_fdot2(__builtin_bit_cast(h2v, w),
                                __builtin_bit_cast(h2v, v), acc, false);
#else
  h2v a = __builtin_bit_cast(h2v, w), b = __builtin_bit_cast(h2v, v);
  return acc + (float)a.x * (float)b.x + (float)a.y * (float)b.y;
#endif
}
__device__ __forceinline__ float dotq(uint4 w, uint4 h, float acc) {
  acc = fdot2(w.x, h.x, acc); acc = fdot2(w.y, h.y, acc);
  acc = fdot2(w.z, h.z, acc); acc = fdot2(w.w, h.w, acc);
  return acc;
}
__device__ __forceinline__ unsigned pack2(float a, float b) {
  h2v h; h.x = (_Float16)a; h.y = (_Float16)b;
  return __builtin_bit_cast(unsigned, h);
}

// L2-bypassing (coherent) accesses for cross-block activation data
__device__ __forceinline__ unsigned long long cohL(const unsigned long long* p) {
  return __hip_atomic_load(p, __ATOMIC_RELAXED, __HIP_MEMORY_SCOPE_SYSTEM);
}
__device__ __forceinline__ void cohS(unsigned long long* p, unsigned long long v) {
  __hip_atomic_store(p, v, __ATOMIC_RELAXED, __HIP_MEMORY_SCOPE_SYSTEM);
}
__device__ __forceinline__ float cohLf(const float* p) {
  return __hip_atomic_load(p, __ATOMIC_RELAXED, __HIP_MEMORY_SCOPE_SYSTEM);
}
__device__ __forceinline__ void cohSf(float* p, float v) {
  __hip_atomic_store(p, v, __ATOMIC_RELAXED, __HIP_MEMORY_SCOPE_SYSTEM);
}

// ---- fence-free distributed COHORT barrier (64 blocks; 16 lines per cohort) ----
__device__ __forceinline__ void bar_arrive(unsigned* ctrs, int line) {
  __syncthreads();   // drains vmcnt: all coherent stores reached L3 before counter bump
  if (threadIdx.x == 0)
    __hip_atomic_fetch_add(&ctrs[line * CSTR], 1u,
                           __ATOMIC_RELAXED, __HIP_MEMORY_SCOPE_AGENT);
}
__device__ __forceinline__ void bar_wait(unsigned* ctrs, int rg, unsigned& ep) {
  ep += 1;
  const unsigned target = ep * 64u;
  if (threadIdx.x < 16) {
    const unsigned* myc = &ctrs[(rg * 16 + threadIdx.x) * CSTR];
    for (;;) {
      unsigned s = __hip_atomic_load(myc, __ATOMIC_RELAXED, __HIP_MEMORY_SCOPE_AGENT);
      #pragma unroll
      for (int o = 8; o; o >>= 1) s += __shfl_down(s, o, 16);
      s = __shfl(s, 0, 16);
      if (s >= target) break;
      __builtin_amdgcn_s_sleep(1);
    }
  }
  __syncthreads();
}

// ---------------- prep: pack Wp1/Wp2/Wclf1 to f16 quads; zero barrier counters ----------------
struct PrepArgs { const float *Wp1, *Wp2, *Wclf1; _Float16* dst; unsigned* bar; };

__global__ void prep_pack_kernel(PrepArgs a) {
  const int idx = blockIdx.x * 256 + threadIdx.x;
  if (idx < NLINES * CSTR) a.bar[idx] = 0u;
  if (idx >= PK_TOTAL) return;
  int off, N, K; const float* src;
  if      (idx < PK_WP2)   { off = PK_WP1;   N = 256; K = 512; src = a.Wp1; }
  else if (idx < PK_WCLF1) { off = PK_WP2;   N = 64;  K = 256; src = a.Wp2; }
  else                     { off = PK_WCLF1; N = 64;  K = 512; src = a.Wclf1; }
  const int li = idx - off, e = li & 7, t2 = li >> 3, j = t2 % N, k8 = t2 / N;
  a.dst[idx] = (_Float16)src[(size_t)j * K + k8 * 8 + e];
}

// ---------------- main persistent kernel ----------------
struct CoopArgs {
  const float *cov, *X, *M;
  const float *Wc1, *bc1, *Wc2, *bc2;
  const float *Whr, *Whz, *Whh;
  const float *bp1, *bp2;
  const float *w_prep, *bias_prep;
  const float *W_ih, *W_hh, *b_ih, *b_hh;
  const float *bclf1, *Wclf2, *bclf2;
  const uint4 *Wp1Q, *Wp2Q, *Wclf1Q;
  unsigned long long *hA, *hB, *rh, *gi;   // u64 views of f16 arrays
  float *h0f, *obs;
  unsigned* bar;
  float* out;
};

__global__ __launch_bounds__(NT)
void gruode_coop(CoopArgs a) {
  const int bid = blockIdx.x, tid = threadIdx.x;
  const int cg = bid >> 2, rg = bid & 3;
  const int g = rg * 64 + cg;                  // duty row (within own cohort!)
  const int c_loc = tid >> 6, r_loc = tid & 63;
  const int c = cg * 8 + c_loc, r = rg * 64 + r_loc;
  const int line = rg * 16 + (cg & 15);        // barrier arrival line

  // LDS-resident weight slices for the 8 owned columns (~72KB)
  __shared__ __align__(16) uint4 WabL[3][8][64];      // Whr/Whz/Whh rows
  __shared__ __align__(16) uint4 WgL[2][3][8][64];    // W_ih/W_hh gate rows
  __shared__ __align__(16) uint4 stageQ[64 * 64];     // [quad][row] staged activations, 64KB
  __shared__ __align__(16) uint4 hrowQ[64];
  __shared__ __align__(16) uint4 qrowQ[32];
  __shared__ __align__(8)  _Float16 outH[512];
  __shared__ __align__(8)  _Float16 giH[512];
  __shared__ float h0L[512];
  __shared__ float wprepL[Dn * 4 * PREPn];
  __shared__ float bprepL[Dn * PREPn];
  __shared__ float bp1L[PHn], bp2L[2 * Dn], pL[2 * Dn];
  __shared__ float xrowL[Dn], mrowL[Dn];
  __shared__ float bclfL[CLFHn], wclf2L[CLFHn], bgL[48];
  __shared__ float covL[COVn], t1L[COVHn];
  __shared__ float obsL[64];

  unsigned long long* stageU = (unsigned long long*)stageQ;
  unsigned long long* outU   = (unsigned long long*)outH;
  unsigned long long* giU    = (unsigned long long*)giH;
  unsigned long long* hrowU  = (unsigned long long*)hrowQ;

  // ---- one-time: stage owned weight slices f32 -> f16 quads in LDS ----
  for (int n = tid; n < 4608; n += NT) {
    const float* srow; uint4* dst; int q;
    if (n < 1536) {
      const int m = n >> 9, rem = n & 511, cl = rem >> 6; q = rem & 63;
      const float* W = (m == 0) ? a.Whr : (m == 1) ? a.Whz : a.Whh;
      srow = W + (size_t)(cg * 8 + cl) * Hn;
      dst = &WabL[m][cl][0];
    } else {
      const int n2 = n - 1536;
      const int mat = n2 / 1536, rem = n2 % 1536, gate = rem / 512, w2 = rem % 512;
      const int cl = w2 >> 6; q = w2 & 63;
      const float* W = mat ? a.W_hh : a.W_ih;
      srow = W + (size_t)(gate * Hn + cg * 8 + cl) * Hn;
      dst = &WgL[mat][gate][cl][0];
    }
    const float* s8 = srow + q * 8;
    uint4 u;
    u.x = pack2(s8[0], s8[1]); u.y = pack2(s8[2], s8[3]);
    u.z = pack2(s8[4], s8[5]); u.w = pack2(s8[6], s8[7]);
    dst[q] = u;
  }
  for (int i = tid; i < Dn * 4 * PREPn; i += NT) wprepL[i] = a.w_prep[i];
  bprepL[tid & 511] = a.bias_prep[tid & 511];
  if (tid < PHn)    bp1L[tid] = a.bp1[tid];
  if (tid < 2 * Dn) bp2L[tid] = a.bp2[tid];
  if (tid < CLFHn)  { bclfL[tid] = a.bclf1[tid]; wclf2L[tid] = a.Wclf2[tid]; }
  if (tid < 48) {
    const int cl = tid / 6, rem = tid % 6, gate = rem >> 1, s = rem & 1;
    const int j = gate * Hn + cg * 8 + cl;
    bgL[tid] = s ? a.b_hh[j] : a.b_ih[j];
  }
  const float bclf2r = a.bclf2[0];

  // ---- h0 for duty-row g ----
  if (tid < COVn) covL[tid] = a.cov[g * COVn + tid];
  __syncthreads();
  if (tid < COVHn) {
    float acc = a.bc1[tid];
    #pragma unroll
    for (int k = 0; k < COVn; ++k) acc += covL[k] * a.Wc1[tid * COVn + k];
    t1L[tid] = fmaxf(acc, 0.0f);
  }
  __syncthreads();
  {
    float acc = a.bc2[tid];
    for (int k = 0; k < COVHn; ++k) acc += t1L[k] * a.Wc2[tid * COVHn + k];
    h0L[tid] = tanhf(acc);
  }
  __syncthreads();
  // publish hA row g (f16, coherent) + h0f row g (f32, coherent)
  if (tid < 128) {
    const int k8 = tid >> 1, half = tid & 1, base = k8 * 8 + half * 4;
    const unsigned lo = pack2(h0L[base], h0L[base + 1]);
    const unsigned hi = pack2(h0L[base + 2], h0L[base + 3]);
    cohS(&a.hA[(size_t)k8 * 512 + g * 2 + half],
         ((unsigned long long)hi << 32) | lo);
  }
  cohSf(&a.h0f[(size_t)g * Hn + tid], h0L[tid]);

  unsigned ep = 0;
  bar_arrive(a.bar, line); bar_wait(a.bar, rg, ep);

  float hfull = cohLf(&a.h0f[(size_t)r * Hn + c]);   // thread-owned f32 h[r,c]
  float zz = 0.f, hbc = 0.f;

  const size_t oub = (size_t)(cg * 256 + rg * 64) * 2;   // u64 base of block's output region

  // stage 64 owned rows of a [quad][256 rows][8] f16 array into stageQ
  auto stage_fill = [&](const unsigned long long* A) {
    #pragma unroll
    for (int i = 0; i < 16; ++i) {
      const int idx = tid + i * NT;              // 0..8191
      const int q = idx >> 7, lane7 = idx & 127;
      stageU[idx] = cohL(&A[(size_t)q * 512 + rg * 128 + lane7]);
    }
  };
  auto do_clf = [&](int tout) {
    if (tid < 128) hrowU[tid] = cohL(&a.hA[(size_t)(tid >> 1) * 512 + g * 2 + (tid & 1)]);
    __syncthreads();
    if (tid < CLFHn) {
      float acc = bclfL[tid];
      #pragma unroll 8
      for (int q = 0; q < Hn / 8; ++q) acc = dotq(a.Wclf1Q[q * CLFHn + tid], hrowQ[q], acc);
      float cc = fmaxf(acc, 0.0f) * wclf2L[tid];
      #pragma unroll
      for (int o = 32; o; o >>= 1) cc += __shfl_down(cc, o, 64);
      if (tid == 0) a.out[tout * Bn + g] = cc + bclf2r;
    }
  };

  for (int t = 0; t < Tn; ++t) {
    // ---- P1: r,z for owned (r,c); publish rh ----
    stage_fill(a.hA);
    __syncthreads();
    {
      float sr = 0.f, sz = 0.f;
      #pragma unroll 8
      for (int q = 0; q < 64; ++q) {
        const uint4 hq = stageQ[q * 64 + r_loc];
        sr = dotq(WabL[0][c_loc][q], hq, sr);
        sz = dotq(WabL[1][c_loc][q], hq, sz);
      }
      const float rr = sigmoidf(sr);
      zz = sigmoidf(sz);
      outH[r_loc * 8 + c_loc] = (_Float16)(rr * hfull);
    }
    __syncthreads();
    if (tid < 128) cohS(&a.rh[oub + tid], outU[tid]);
    bar_arrive(a.bar, line);
    if (t > 0) do_clf(t - 1);          // hides barrier wait
    bar_wait(a.bar, rg, ep);

    // ---- P2: u = tanh(rh@Whh^T); Euler; publish hB ----
    stage_fill(a.rh);
    __syncthreads();
    {
      float su = 0.f;
      #pragma unroll 8
      for (int q = 0; q < 64; ++q)
        su = dotq(WabL[2][c_loc][q], stageQ[q * 64 + r_loc], su);
      const float u = tanhf(su);
      hbc = hfull + DTc * (1.0f - zz) * (u - hfull);
      outH[r_loc * 8 + c_loc] = (_Float16)hbc;
    }
    __syncthreads();
    if (tid < 128) cohS(&a.hB[oub + tid], outU[tid]);
    bar_arrive(a.bar, line);
    if (tid >= 64 && tid < 96)        xrowL[tid - 64] = a.X[((size_t)t * Bn + g) * Dn + (tid - 64)];
    else if (tid >= 96 && tid < 128)  mrowL[tid - 96] = a.M[((size_t)t * Bn + g) * Dn + (tid - 96)];
    bar_wait(a.bar, rg, ep);

    // ---- P3 (duty-row g): q -> p -> prep -> gi, obs ----
    if (tid < 128) hrowU[tid] = cohL(&a.hB[(size_t)(tid >> 1) * 512 + g * 2 + (tid & 1)]);
    __syncthreads();
    if (tid < PHn) {
      float acc = bp1L[tid];
      #pragma unroll 8
      for (int q = 0; q < Hn / 8; ++q)
        acc = dotq(a.Wp1Q[q * PHn + tid], hrowQ[q], acc);
      ((_Float16*)qrowQ)[tid] = (_Float16)fmaxf(acc, 0.0f);
    }
    __syncthreads();
    if (tid < 2 * Dn) {
      float acc = bp2L[tid];
      #pragma unroll 4
      for (int q = 0; q < PHn / 8; ++q)
        acc = dotq(a.Wp2Q[q * (2 * Dn) + tid], qrowQ[q], acc);
      pL[tid] = acc;
    }
    __syncthreads();
    {
      const int d = tid >> 4, pp = tid & 15;
      const float xv   = xrowL[d];
      const float mean = pL[d];
      const float logv = pL[Dn + d];
      const float err  = (xv - mean) * __expf(-0.5f * logv);
      float acc = bprepL[d * PREPn + pp];
      acc += xv   * wprepL[(d * 4 + 0) * PREPn + pp];
      acc += mean * wprepL[(d * 4 + 1) * PREPn + pp];
      acc += logv * wprepL[(d * 4 + 2) * PREPn + pp];
      acc += err  * wprepL[(d * 4 + 3) * PREPn + pp];
      giH[tid] = (_Float16)(fmaxf(acc, 0.0f) * mrowL[d]);
      if (tid < 32) {
        const unsigned long long bb = __ballot(mrowL[tid] > 0.0f);
        if (tid == 0) cohSf(&a.obs[g], bb ? 1.0f : 0.0f);
      }
    }
    __syncthreads();
    if (tid < 128) cohS(&a.gi[(size_t)(tid >> 1) * 512 + g * 2 + (tid & 1)], giU[tid]);
    bar_arrive(a.bar, line);           // b3 arrive EARLY

    // ---- P4 h-side hidden under b3: stage hB; W_hh gate dots ----
    stage_fill(a.hB);
    __syncthreads();
    float gr  = bgL[c_loc * 6 + 0] + bgL[c_loc * 6 + 1];
    float gz  = bgL[c_loc * 6 + 2] + bgL[c_loc * 6 + 3];
    float xn  = bgL[c_loc * 6 + 4];
    float hnb = bgL[c_loc * 6 + 5];
    #pragma unroll 4
    for (int q = 0; q < 64; ++q) {
      const uint4 hq = stageQ[q * 64 + r_loc];
      gr  = dotq(WgL[1][0][c_loc][q], hq, gr);
      gz  = dotq(WgL[1][1][c_loc][q], hq, gz);
      hnb = dotq(WgL[1][2][c_loc][q], hq, hnb);
    }
    bar_wait(a.bar, rg, ep);           // gi from cohort now visible

    // ---- P4 x-side: stage gi; W_ih gate dots; combine; publish hA ----
    stage_fill(a.gi);
    if (tid < 64) obsL[tid] = cohLf(&a.obs[rg * 64 + tid]);
    __syncthreads();
    #pragma unroll 4
    for (int q = 0; q < 64; ++q) {
      const uint4 gq = stageQ[q * 64 + r_loc];
      gr = dotq(WgL[0][0][c_loc][q], gq, gr);
      gz = dotq(WgL[0][1][c_loc][q], gq, gz);
      xn = dotq(WgL[0][2][c_loc][q], gq, xn);
    }
    {
      const float rgg = sigmoidf(gr);
      const float zgg = sigmoidf(gz);
      const float ng  = tanhf(xn + rgg * hnb);
      hfull = (obsL[r_loc] > 0.0f) ? ((1.0f - zgg) * ng + zgg * hbc) : hbc;
      outH[r_loc * 8 + c_loc] = (_Float16)hfull;
    }
    __syncthreads();
    if (tid < 128) cohS(&a.hA[oub + tid], outU[tid]);
    bar_arrive(a.bar, line);
    bar_wait(a.bar, rg, ep);
  }

  do_clf(Tn - 1);
}

extern "C" void kernel_launch(void* const* d_in, const int* in_sizes, int n_in,
                              void* d_out, int out_size, void* d_ws, size_t ws_size,
                              hipStream_t stream) {
  char* ws = (char*)d_ws;

  CoopArgs a;
  a.cov  = (const float*)d_in[0];
  a.X    = (const float*)d_in[1];
  a.M    = (const float*)d_in[2];
  a.Wc1  = (const float*)d_in[3];  a.bc1 = (const float*)d_in[4];
  a.Wc2  = (const float*)d_in[5];  a.bc2 = (const float*)d_in[6];
  a.Whr  = (const float*)d_in[7];  a.Whz = (const float*)d_in[8];  a.Whh = (const float*)d_in[9];
  const float* Wp1 = (const float*)d_in[10]; a.bp1 = (const float*)d_in[11];
  const float* Wp2 = (const float*)d_in[12]; a.bp2 = (const float*)d_in[13];
  a.w_prep = (const float*)d_in[14]; a.bias_prep = (const float*)d_in[15];
  a.W_ih = (const float*)d_in[16]; a.W_hh = (const float*)d_in[17];
  a.b_ih = (const float*)d_in[18]; a.b_hh = (const float*)d_in[19];
  const float* Wclf1 = (const float*)d_in[20]; a.bclf1 = (const float*)d_in[21];
  a.Wclf2 = (const float*)d_in[22]; a.bclf2 = (const float*)d_in[23];

  _Float16* pk = (_Float16*)ws;
  a.Wp1Q   = (const uint4*)(pk + PK_WP1);
  a.Wp2Q   = (const uint4*)(pk + PK_WP2);
  a.Wclf1Q = (const uint4*)(pk + PK_WCLF1);
  a.hA  = (unsigned long long*)(ws + WS_HA);
  a.hB  = (unsigned long long*)(ws + WS_HB);
  a.rh  = (unsigned long long*)(ws + WS_RH);
  a.gi  = (unsigned long long*)(ws + WS_GI);
  a.h0f = (float*)(ws + WS_H0F);
  a.obs = (float*)(ws + WS_OBS);
  a.bar = (unsigned*)(ws + WS_BAR);
  a.out = (float*)d_out;

  PrepArgs p;
  p.Wp1 = Wp1; p.Wp2 = Wp2; p.Wclf1 = Wclf1;
  p.dst = pk; p.bar = a.bar;
  prep_pack_kernel<<<(PK_TOTAL + 255) / 256, 256, 0, stream>>>(p);
  gruode_coop<<<Bn, NT, 0, stream>>>(a);
}

// Round 7
// 6705.266 us; speedup vs baseline: 3.8215x; 1.4240x over previous
//
#include <hip/hip_runtime.h>
#include <hip/hip_bf16.h>

// Problem constants
constexpr int Bn = 256, Tn = 200, Dn = 32, Hn = 512, PHn = 256, PREPn = 16;
constexpr int COVn = 32, COVHn = 128, CLFHn = 64;
constexpr float DTc = 0.05f;
constexpr int NT = 512;
// grid = 256 blocks = 64 col-groups x 4 row-groups (rg = bid&3; each XCD hosts ONE cohort).
// block (cg,rg): owns H-cols [8cg,8cg+8) (= quad cg) x batch-rows [64rg,64rg+64); duty row g = rg*64+cg.

constexpr int CSTR = 32;               // barrier counter line stride in u32 (128B)
constexpr int NLINES = 64;             // 4 cohorts x 16 lines

typedef _Float16 h2v __attribute__((ext_vector_type(2)));

// packed f16 quad layout for streamed matrices: elem (k,j) of [N,K] at ((k>>3)*N + j)*8 + (k&7)
constexpr int PK_WP1   = 0;        // 256x512
constexpr int PK_WP2   = 131072;   // 64x256
constexpr int PK_WCLF1 = 147456;   // 64x512
constexpr int PK_TOTAL = 180224;

// ws byte offsets.
// Activation ring: 4 arrays (hA,rh,hB,gi) x 4 step-parity buffers, each slab
// f16 [64 quads][256 rows][8] = 256KB. Coherence: sys-scope writes (-> L3) +
// cached reads + fence(acquire,agent) every 4 steps => cached copy of a slab
// address is always invalidated between its re-writes (exactly one inv in any
// 4 consecutive steps; reuse distance is exactly 4 steps).
constexpr size_t WS_ACT = 393216;      // 16 x 262144 -> ends 4587520
constexpr size_t WS_OBS = 4587520;     // 4 bufs x 256 f32
constexpr size_t WS_BAR = 4591616;     // NLINES*CSTR u32, zeroed by prep kernel

__device__ __forceinline__ float sigmoidf(float x) { return 1.0f / (1.0f + __expf(-x)); }

__device__ __forceinline__ float fdot2(unsigned w, unsigned v, float acc) {
#if __has_builtin(__builtin_amdgcn_fdot2)
  return __builtin_amdgcn_fdot2(__builtin_bit_cast(h2v, w),
                                __builtin_bit_cast(h2v, v), acc, false);
#else
  h2v a = __builtin_bit_cast(h2v, w), b = __builtin_bit_cast(h2v, v);
  return acc + (float)a.x * (float)b.x + (float)a.y * (float)b.y;
#endif
}
__device__ __forceinline__ float dotq(uint4 w, uint4 h, float acc) {
  acc = fdot2(w.x, h.x, acc); acc = fdot2(w.y, h.y, acc);
  acc = fdot2(w.z, h.z, acc); acc = fdot2(w.w, h.w, acc);
  return acc;
}
__device__ __forceinline__ unsigned pack2(float a, float b) {
  h2v h; h.x = (_Float16)a; h.y = (_Float16)b;
  return __builtin_bit_cast(unsigned, h);
}

// system-scope (L2-bypass) ops: only for cross-block WRITES now
__device__ __forceinline__ void cohS(unsigned long long* p, unsigned long long v) {
  __hip_atomic_store(p, v, __ATOMIC_RELAXED, __HIP_MEMORY_SCOPE_SYSTEM);
}
__device__ __forceinline__ void cohSf(float* p, float v) {
  __hip_atomic_store(p, v, __ATOMIC_RELAXED, __HIP_MEMORY_SCOPE_SYSTEM);
}

// ---- fence-free distributed COHORT barrier (64 blocks; 16 lines per cohort) ----
__device__ __forceinline__ void bar_arrive(unsigned* ctrs, int line) {
  __syncthreads();   // drains vmcnt: all sys-scope stores reached L3 before counter bump
  if (threadIdx.x == 0)
    __hip_atomic_fetch_add(&ctrs[line * CSTR], 1u,
                           __ATOMIC_RELAXED, __HIP_MEMORY_SCOPE_AGENT);
}
__device__ __forceinline__ void bar_wait(unsigned* ctrs, int rg, unsigned& ep) {
  ep += 1;
  const unsigned target = ep * 64u;
  if (threadIdx.x < 16) {
    const unsigned* myc = &ctrs[(rg * 16 + threadIdx.x) * CSTR];
    for (;;) {
      unsigned s = __hip_atomic_load(myc, __ATOMIC_RELAXED, __HIP_MEMORY_SCOPE_AGENT);
      #pragma unroll
      for (int o = 8; o; o >>= 1) s += __shfl_down(s, o, 16);
      s = __shfl(s, 0, 16);
      if (s >= target) break;
      __builtin_amdgcn_s_sleep(1);
    }
  }
  __syncthreads();
}

// ---------------- prep: pack Wp1/Wp2/Wclf1 to f16 quads; zero barrier counters ----------------
struct PrepArgs { const float *Wp1, *Wp2, *Wclf1; _Float16* dst; unsigned* bar; };

__global__ void prep_pack_kernel(PrepArgs a) {
  const int idx = blockIdx.x * 256 + threadIdx.x;
  if (idx < NLINES * CSTR) a.bar[idx] = 0u;
  if (idx >= PK_TOTAL) return;
  int off, N, K; const float* src;
  if      (idx < PK_WP2)   { off = PK_WP1;   N = 256; K = 512; src = a.Wp1; }
  else if (idx < PK_WCLF1) { off = PK_WP2;   N = 64;  K = 256; src = a.Wp2; }
  else                     { off = PK_WCLF1; N = 64;  K = 512; src = a.Wclf1; }
  const int li = idx - off, e = li & 7, t2 = li >> 3, j = t2 % N, k8 = t2 / N;
  a.dst[idx] = (_Float16)src[(size_t)j * K + k8 * 8 + e];
}

// ---------------- main persistent kernel ----------------
struct CoopArgs {
  const float *cov, *X, *M;
  const float *Wc1, *bc1, *Wc2, *bc2;
  const float *Whr, *Whz, *Whh;
  const float *bp1, *bp2;
  const float *w_prep, *bias_prep;
  const float *W_ih, *W_hh, *b_ih, *b_hh;
  const float *bclf1, *Wclf2, *bclf2;
  const uint4 *Wp1Q, *Wp2Q, *Wclf1Q;
  char* act;          // 16 slabs base
  float* obs;         // 4 x 256
  unsigned* bar;
  float* out;
};

__global__ __launch_bounds__(NT)
void gruode_coop(CoopArgs a) {
  const int bid = blockIdx.x, tid = threadIdx.x;
  const int cg = bid >> 2, rg = bid & 3;
  const int g = rg * 64 + cg;                  // duty row (inside own cohort's row range)
  const int c_loc = tid >> 6, r_loc = tid & 63;
  const int c = cg * 8 + c_loc;
  const int line = rg * 16 + (cg & 15);

  __shared__ __align__(16) uint4 WabL[3][8][64];      // Whr/Whz/Whh rows (24KB)
  __shared__ __align__(16) uint4 WgL[2][3][8][64];    // W_ih/W_hh gate rows (48KB)
  __shared__ __align__(16) uint4 stageQ[64 * 64];     // [quad][row] staged slab, 64KB
  __shared__ __align__(16) uint4 hrowQ[64];
  __shared__ __align__(16) uint4 qrowQ[32];
  __shared__ __align__(8)  _Float16 outH[512];
  __shared__ __align__(8)  _Float16 giH[512];
  __shared__ float wprepL[Dn * 4 * PREPn];
  __shared__ float bprepL[Dn * PREPn];
  __shared__ float bp1L[PHn], bp2L[2 * Dn], pL[2 * Dn];
  __shared__ float xrowL[Dn], mrowL[Dn];
  __shared__ float bclfL[CLFHn], wclf2L[CLFHn], bgL[48];
  __shared__ float obsL[64];

  unsigned long long* outU = (unsigned long long*)outH;
  unsigned long long* giU  = (unsigned long long*)giH;

  auto slabp = [&](int arr, int buf) -> uint4* {
    return (uint4*)(a.act + ((size_t)(arr * 4 + buf) << 18));
  };

  // ---- one-time: stage owned weight slices f32 -> f16 quads in LDS ----
  for (int n = tid; n < 4608; n += NT) {
    const float* srow; uint4* dst; int q;
    if (n < 1536) {
      const int m = n >> 9, rem = n & 511, cl = rem >> 6; q = rem & 63;
      const float* W = (m == 0) ? a.Whr : (m == 1) ? a.Whz : a.Whh;
      srow = W + (size_t)(cg * 8 + cl) * Hn;
      dst = &WabL[m][cl][0];
    } else {
      const int n2 = n - 1536;
      const int mat = n2 / 1536, rem = n2 % 1536, gate = rem / 512, w2 = rem % 512;
      const int cl = w2 >> 6; q = w2 & 63;
      const float* W = mat ? a.W_hh : a.W_ih;
      srow = W + (size_t)(gate * Hn + cg * 8 + cl) * Hn;
      dst = &WgL[mat][gate][cl][0];
    }
    const float* s8 = srow + q * 8;
    uint4 u;
    u.x = pack2(s8[0], s8[1]); u.y = pack2(s8[2], s8[3]);
    u.z = pack2(s8[4], s8[5]); u.w = pack2(s8[6], s8[7]);
    dst[q] = u;
  }
  for (int i = tid; i < Dn * 4 * PREPn; i += NT) wprepL[i] = a.w_prep[i];
  bprepL[tid & 511] = a.bias_prep[tid & 511];
  if (tid < PHn)    bp1L[tid] = a.bp1[tid];
  if (tid < 2 * Dn) bp2L[tid] = a.bp2[tid];
  if (tid < CLFHn)  { bclfL[tid] = a.bclf1[tid]; wclf2L[tid] = a.Wclf2[tid]; }
  if (tid < 48) {
    const int cl = tid / 6, rem = tid % 6, gate = rem >> 1, s = rem & 1;
    const int j = gate * Hn + cg * 8 + cl;
    bgL[tid] = s ? a.b_hh[j] : a.b_ih[j];
  }
  const float bclf2r = a.bclf2[0];

  // ---- h0 computed per block in f32 for its 64 rows x 8 cols (no exchange) ----
  float hfull;
  {
    float* covF = (float*)stageQ;            // [64][32] f32
    float* midF = covF + 64 * 32;            // [64][128] f32
    __syncthreads();
    for (int i = tid; i < 64 * 32; i += NT)
      covF[i] = a.cov[(size_t)(rg * 64) * COVn + i];
    __syncthreads();
    for (int i = tid; i < 64 * 128; i += NT) {
      const int rr = i >> 7, m = i & 127;
      float acc = a.bc1[m];
      #pragma unroll 8
      for (int k = 0; k < COVn; ++k) acc += covF[rr * 32 + k] * a.Wc1[m * COVn + k];
      midF[i] = fmaxf(acc, 0.0f);
    }
    __syncthreads();
    {
      float acc = a.bc2[c];
      const float* w2 = a.Wc2 + (size_t)c * COVHn;
      #pragma unroll 4
      for (int k = 0; k < COVHn; ++k) acc += midF[r_loc * 128 + k] * w2[k];
      hfull = tanhf(acc);
      outH[r_loc * 8 + c_loc] = (_Float16)hfull;
    }
    __syncthreads();
    // publish block's own (rows x cols) region of hA buf 3 ("step -1")
    unsigned long long* hA3u = (unsigned long long*)slabp(0, 3);
    const size_t oub0 = (size_t)(cg * 256 + rg * 64) * 2;
    if (tid < 128) cohS(&hA3u[oub0 + tid], outU[tid]);
  }

  unsigned ep = 0;
  bar_arrive(a.bar, line); bar_wait(a.bar, rg, ep);

  float zz = 0.f, hbc = 0.f;
  const size_t oub = (size_t)(cg * 256 + rg * 64) * 2;   // u64 base of block's slab region

  // cached stage of cohort's 64 rows of a slab into stageQ ([quad][row] uint4)
  auto stage_fill = [&](const uint4* A) {
    #pragma unroll
    for (int i = 0; i < 8; ++i) {
      const int idx = tid + i * NT;              // 0..4095 = quad*64 + row
      const int q = idx >> 6, rr = idx & 63;
      stageQ[idx] = A[q * 256 + rg * 64 + rr];
    }
  };
  auto do_clf = [&](const uint4* hAbase, int tout) {
    if (tid < 64) hrowQ[tid] = hAbase[tid * 256 + g];
    __syncthreads();
    if (tid < CLFHn) {
      float acc = bclfL[tid];
      #pragma unroll 8
      for (int q = 0; q < Hn / 8; ++q) acc = dotq(a.Wclf1Q[q * CLFHn + tid], hrowQ[q], acc);
      float cc = fmaxf(acc, 0.0f) * wclf2L[tid];
      #pragma unroll
      for (int o = 32; o; o >>= 1) cc += __shfl_down(cc, o, 64);
      if (tid == 0) a.out[tout * Bn + g] = cc + bclf2r;
    }
  };

  for (int t = 0; t < Tn; ++t) {
    // synchronized L1+L2 invalidate once per ring period (all blocks on an XCD
    // are same-cohort => they fence at the same point)
    if ((t & 3) == 0) __builtin_amdgcn_fence(__ATOMIC_ACQUIRE, "agent");

    const int bs = t & 3, bp = (t + 3) & 3;
    const uint4* hA_prev = slabp(0, bp);
    uint4* rh_cur = slabp(1, bs);
    uint4* hB_cur = slabp(2, bs);
    uint4* gi_cur = slabp(3, bs);
    uint4* hA_cur = slabp(0, bs);
    float* obs_cur = a.obs + bs * 256;

    // ---- P1: r,z for owned (r,c); publish rh ----
    stage_fill(hA_prev);
    __syncthreads();
    {
      float sr = 0.f, sz = 0.f;
      #pragma unroll 8
      for (int q = 0; q < 64; ++q) {
        const uint4 hq = stageQ[q * 64 + r_loc];
        sr = dotq(WabL[0][c_loc][q], hq, sr);
        sz = dotq(WabL[1][c_loc][q], hq, sz);
      }
      const float rr = sigmoidf(sr);
      zz = sigmoidf(sz);
      outH[r_loc * 8 + c_loc] = (_Float16)(rr * hfull);
    }
    __syncthreads();
    if (tid < 128) cohS(((unsigned long long*)rh_cur) + oub + tid, outU[tid]);
    bar_arrive(a.bar, line);
    if (t > 0) do_clf(hA_prev, t - 1);          // hides barrier wait
    bar_wait(a.bar, rg, ep);

    // ---- P2: u = tanh(rh@Whh^T); Euler; publish hB ----
    stage_fill(rh_cur);
    __syncthreads();
    {
      float su = 0.f;
      #pragma unroll 8
      for (int q = 0; q < 64; ++q)
        su = dotq(WabL[2][c_loc][q], stageQ[q * 64 + r_loc], su);
      const float u = tanhf(su);
      hbc = hfull + DTc * (1.0f - zz) * (u - hfull);
      outH[r_loc * 8 + c_loc] = (_Float16)hbc;
    }
    __syncthreads();
    if (tid < 128) cohS(((unsigned long long*)hB_cur) + oub + tid, outU[tid]);
    bar_arrive(a.bar, line);
    if (tid >= 64 && tid < 96)        xrowL[tid - 64] = a.X[((size_t)t * Bn + g) * Dn + (tid - 64)];
    else if (tid >= 96 && tid < 128)  mrowL[tid - 96] = a.M[((size_t)t * Bn + g) * Dn + (tid - 96)];
    bar_wait(a.bar, rg, ep);

    // ---- P3 (duty-row g): q -> p -> prep -> gi, obs ----
    if (tid < 64) hrowQ[tid] = hB_cur[tid * 256 + g];
    __syncthreads();
    if (tid < PHn) {
      float acc = bp1L[tid];
      #pragma unroll 8
      for (int q = 0; q < Hn / 8; ++q)
        acc = dotq(a.Wp1Q[q * PHn + tid], hrowQ[q], acc);
      ((_Float16*)qrowQ)[tid] = (_Float16)fmaxf(acc, 0.0f);
    }
    __syncthreads();
    if (tid < 2 * Dn) {
      float acc = bp2L[tid];
      #pragma unroll 4
      for (int q = 0; q < PHn / 8; ++q)
        acc = dotq(a.Wp2Q[q * (2 * Dn) + tid], qrowQ[q], acc);
      pL[tid] = acc;
    }
    __syncthreads();
    {
      const int d = tid >> 4, pp = tid & 15;
      const float xv   = xrowL[d];
      const float mean = pL[d];
      const float logv = pL[Dn + d];
      const float err  = (xv - mean) * __expf(-0.5f * logv);
      float acc = bprepL[d * PREPn + pp];
      acc += xv   * wprepL[(d * 4 + 0) * PREPn + pp];
      acc += mean * wprepL[(d * 4 + 1) * PREPn + pp];
      acc += logv * wprepL[(d * 4 + 2) * PREPn + pp];
      acc += err  * wprepL[(d * 4 + 3) * PREPn + pp];
      giH[tid] = (_Float16)(fmaxf(acc, 0.0f) * mrowL[d]);
      if (tid < 32) {
        const unsigned long long bb = __ballot(mrowL[tid] > 0.0f);
        if (tid == 0) cohSf(&obs_cur[g], bb ? 1.0f : 0.0f);
      }
    }
    __syncthreads();
    if (tid < 128)
      cohS(((unsigned long long*)gi_cur) + (size_t)(tid >> 1) * 512 + g * 2 + (tid & 1), giU[tid]);
    bar_arrive(a.bar, line);           // b3 arrive EARLY

    // ---- P4 h-side hidden under b3: stage hB; W_hh gate dots ----
    stage_fill(hB_cur);
    __syncthreads();
    float gr  = bgL[c_loc * 6 + 0] + bgL[c_loc * 6 + 1];
    float gz  = bgL[c_loc * 6 + 2] + bgL[c_loc * 6 + 3];
    float xn  = bgL[c_loc * 6 + 4];
    float hnb = bgL[c_loc * 6 + 5];
    #pragma unroll 4
    for (int q = 0; q < 64; ++q) {
      const uint4 hq = stageQ[q * 64 + r_loc];
      gr  = dotq(WgL[1][0][c_loc][q], hq, gr);
      gz  = dotq(WgL[1][1][c_loc][q], hq, gz);
      hnb = dotq(WgL[1][2][c_loc][q], hq, hnb);
    }
    bar_wait(a.bar, rg, ep);           // cohort's gi now visible

    // ---- P4 x-side: stage gi; W_ih gate dots; combine; publish hA ----
    stage_fill(gi_cur);
    if (tid < 64) obsL[tid] = obs_cur[rg * 64 + tid];
    __syncthreads();
    #pragma unroll 4
    for (int q = 0; q < 64; ++q) {
      const uint4 gq = stageQ[q * 64 + r_loc];
      gr = dotq(WgL[0][0][c_loc][q], gq, gr);
      gz = dotq(WgL[0][1][c_loc][q], gq, gz);
      xn = dotq(WgL[0][2][c_loc][q], gq, xn);
    }
    {
      const float rgg = sigmoidf(gr);
      const float zgg = sigmoidf(gz);
      const float ng  = tanhf(xn + rgg * hnb);
      hfull = (obsL[r_loc] > 0.0f) ? ((1.0f - zgg) * ng + zgg * hbc) : hbc;
      outH[r_loc * 8 + c_loc] = (_Float16)hfull;
    }
    __syncthreads();
    if (tid < 128) cohS(((unsigned long long*)hA_cur) + oub + tid, outU[tid]);
    bar_arrive(a.bar, line);
    bar_wait(a.bar, rg, ep);
  }

  do_clf(slabp(0, (Tn - 1) & 3), Tn - 1);
}

extern "C" void kernel_launch(void* const* d_in, const int* in_sizes, int n_in,
                              void* d_out, int out_size, void* d_ws, size_t ws_size,
                              hipStream_t stream) {
  char* ws = (char*)d_ws;

  CoopArgs a;
  a.cov  = (const float*)d_in[0];
  a.X    = (const float*)d_in[1];
  a.M    = (const float*)d_in[2];
  a.Wc1  = (const float*)d_in[3];  a.bc1 = (const float*)d_in[4];
  a.Wc2  = (const float*)d_in[5];  a.bc2 = (const float*)d_in[6];
  a.Whr  = (const float*)d_in[7];  a.Whz = (const float*)d_in[8];  a.Whh = (const float*)d_in[9];
  const float* Wp1 = (const float*)d_in[10]; a.bp1 = (const float*)d_in[11];
  const float* Wp2 = (const float*)d_in[12]; a.bp2 = (const float*)d_in[13];
  a.w_prep = (const float*)d_in[14]; a.bias_prep = (const float*)d_in[15];
  a.W_ih = (const float*)d_in[16]; a.W_hh = (const float*)d_in[17];
  a.b_ih = (const float*)d_in[18]; a.b_hh = (const float*)d_in[19];
  const float* Wclf1 = (const float*)d_in[20]; a.bclf1 = (const float*)d_in[21];
  a.Wclf2 = (const float*)d_in[22]; a.bclf2 = (const float*)d_in[23];

  _Float16* pk = (_Float16*)ws;
  a.Wp1Q   = (const uint4*)(pk + PK_WP1);
  a.Wp2Q   = (const uint4*)(pk + PK_WP2);
  a.Wclf1Q = (const uint4*)(pk + PK_WCLF1);
  a.act = ws + WS_ACT;
  a.obs = (float*)(ws + WS_OBS);
  a.bar = (unsigned*)(ws + WS_BAR);
  a.out = (float*)d_out;

  PrepArgs p;
  p.Wp1 = Wp1; p.Wp2 = Wp2; p.Wclf1 = Wclf1;
  p.dst = pk; p.bar = a.bar;
  prep_pack_kernel<<<(PK_TOTAL + 255) / 256, 256, 0, stream>>>(p);
  gruode_coop<<<Bn, NT, 0, stream>>>(a);
}

// Round 9
// 5689.140 us; speedup vs baseline: 4.5040x; 1.1786x over previous
//
#include <hip/hip_runtime.h>
#include <hip/hip_bf16.h>

// Problem constants
constexpr int Bn = 256, Tn = 200, Dn = 32, Hn = 512, PHn = 256, PREPn = 16;
constexpr int COVn = 32, COVHn = 128, CLFHn = 64;
constexpr float DTc = 0.05f;
constexpr int NT = 512;
// grid = 256 blocks = 64 col-groups x 4 row-groups (1 block/CU, proven co-resident).
// block (cg,rg): owns H-cols [8cg,8cg+8) (= slab quad cg) x batch-rows [64rg,64rg+64);
// duty row g = rg*64+cg. 4 rg-cohorts of 64 blocks are independent (cohort barriers).

constexpr int CSTR = 32;               // barrier counter line stride in u32 (128B)
constexpr int NLINES = 64;             // 4 cohorts x 16 lines

typedef _Float16 h2v __attribute__((ext_vector_type(2)));
typedef _Float16 f16x8 __attribute__((ext_vector_type(8)));
typedef float f32x4 __attribute__((ext_vector_type(4)));

// packed f16 quad layout for streamed matrices: elem (k,j) of [N,K] at ((k>>3)*N + j)*8 + (k&7)
constexpr int PK_WP1   = 0;        // 256x512
constexpr int PK_WP2   = 131072;   // 64x256
constexpr int PK_WCLF1 = 147456;   // 64x512
constexpr int PK_TOTAL = 180224;

// ws byte offsets. Activation ring: 4 arrays (hA,rh,hB,gi) x 4 step-parity
// buffers, slab = f16 [64 quads][256 rows][8] = 256KB. Coherence: sys-scope
// writes (to L3) + cached reads + fence(acquire,agent) every 4 steps.
constexpr size_t WS_ACT = 393216;      // 16 x 262144 -> ends 4587520
constexpr size_t WS_OBS = 4587520;     // 4 bufs x 256 f32
constexpr size_t WS_BAR = 4591616;     // NLINES*CSTR u32, zeroed by prep

__device__ __forceinline__ float sigmoidf(float x) { return 1.0f / (1.0f + __expf(-x)); }

__device__ __forceinline__ float fdot2(unsigned w, unsigned v, float acc) {
#if __has_builtin(__builtin_amdgcn_fdot2)
  return __builtin_amdgcn_fdot2(__builtin_bit_cast(h2v, w),
                                __builtin_bit_cast(h2v, v), acc, false);
#else
  h2v a = __builtin_bit_cast(h2v, w), b = __builtin_bit_cast(h2v, v);
  return acc + (float)a.x * (float)b.x + (float)a.y * (float)b.y;
#endif
}
__device__ __forceinline__ float dotq(uint4 w, uint4 h, float acc) {
  acc = fdot2(w.x, h.x, acc); acc = fdot2(w.y, h.y, acc);
  acc = fdot2(w.z, h.z, acc); acc = fdot2(w.w, h.w, acc);
  return acc;
}
__device__ __forceinline__ unsigned pack2(float a, float b) {
  h2v h; h.x = (_Float16)a; h.y = (_Float16)b;
  return __builtin_bit_cast(unsigned, h);
}

// system-scope (L2-bypass) stores for cross-block activation writes
__device__ __forceinline__ void cohS(unsigned long long* p, unsigned long long v) {
  __hip_atomic_store(p, v, __ATOMIC_RELAXED, __HIP_MEMORY_SCOPE_SYSTEM);
}
__device__ __forceinline__ void cohSf(float* p, float v) {
  __hip_atomic_store(p, v, __ATOMIC_RELAXED, __HIP_MEMORY_SCOPE_SYSTEM);
}

// ---- fence-free distributed COHORT barrier (64 blocks; 16 lines per cohort) ----
__device__ __forceinline__ void bar_arrive(unsigned* ctrs, int line) {
  __syncthreads();   // drains vmcnt: sys-scope stores reached L3 before bump
  if (threadIdx.x == 0)
    __hip_atomic_fetch_add(&ctrs[line * CSTR], 1u,
                           __ATOMIC_RELAXED, __HIP_MEMORY_SCOPE_AGENT);
}
__device__ __forceinline__ void bar_wait(unsigned* ctrs, int rg, unsigned& ep) {
  ep += 1;
  const unsigned target = ep * 64u;
  if (threadIdx.x < 16) {
    const unsigned* myc = &ctrs[(rg * 16 + threadIdx.x) * CSTR];
    for (;;) {
      unsigned s = __hip_atomic_load(myc, __ATOMIC_RELAXED, __HIP_MEMORY_SCOPE_AGENT);
      #pragma unroll
      for (int o = 8; o; o >>= 1) s += __shfl_down(s, o, 16);
      s = __shfl(s, 0, 16);
      if (s >= target) break;
      __builtin_amdgcn_s_sleep(1);
    }
  }
  __syncthreads();
}

// ---------------- prep: pack Wp1/Wp2/Wclf1 to f16 quads; zero barrier counters ----------------
struct PrepArgs { const float *Wp1, *Wp2, *Wclf1; _Float16* dst; unsigned* bar; };

__global__ void prep_pack_kernel(PrepArgs a) {
  const int idx = blockIdx.x * 256 + threadIdx.x;
  if (idx < NLINES * CSTR) a.bar[idx] = 0u;
  if (idx >= PK_TOTAL) return;
  int off, N, K; const float* src;
  if      (idx < PK_WP2)   { off = PK_WP1;   N = 256; K = 512; src = a.Wp1; }
  else if (idx < PK_WCLF1) { off = PK_WP2;   N = 64;  K = 256; src = a.Wp2; }
  else                     { off = PK_WCLF1; N = 64;  K = 512; src = a.Wclf1; }
  const int li = idx - off, e = li & 7, t2 = li >> 3, j = t2 % N, k8 = t2 / N;
  a.dst[idx] = (_Float16)src[(size_t)j * K + k8 * 8 + e];
}

// ---------------- main persistent kernel ----------------
struct CoopArgs {
  const float *cov, *X, *M;
  const float *Wc1, *bc1, *Wc2, *bc2;
  const float *Whr, *Whz, *Whh;
  const float *bp1, *bp2;
  const float *w_prep, *bias_prep;
  const float *W_ih, *W_hh, *b_ih, *b_hh;
  const float *bclf1, *Wclf2, *bclf2;
  const uint4 *Wp1Q, *Wp2Q, *Wclf1Q;
  char* act;          // 16 slabs base
  float* obs;         // 4 x 256
  unsigned* bar;
  float* out;
};

__global__ __launch_bounds__(NT)
void gruode_coop(CoopArgs a) {
  const int bid = blockIdx.x, tid = threadIdx.x;
  const int cg = bid >> 2, rg = bid & 3;
  const int g = rg * 64 + cg;                  // duty row (inside own cohort's rows)
  const int c_loc = tid >> 6, r_loc = tid & 63;
  const int c = cg * 8 + c_loc;
  const int lane = tid & 63, wv = tid >> 6;
  const int mt = wv & 3, kh = wv >> 2;         // MFMA roles: M-tile, k-half
  const int line = rg * 16 + (cg & 15);
  const int rgofs = rg * 64;

  // LDS: weights for MFMA B-operands (paired 16-col + compact 8-col) + stage
  __shared__ __align__(16) uint4 Wrz16[16 * 64];      // Whr|Whz paired (16KB)
  __shared__ __align__(16) uint4 Wxrz16[16 * 64];     // W_ih r|z (16KB)
  __shared__ __align__(16) uint4 Whrz16[16 * 64];     // W_hh r|z (16KB)
  __shared__ __align__(16) uint4 Whh8[8 * 64];        // Whh (8KB)
  __shared__ __align__(16) uint4 Wxn8[8 * 64];        // W_ih n (8KB)
  __shared__ __align__(16) uint4 Whn8[8 * 64];        // W_hh n (8KB)
  __shared__ __align__(16) uint4 stageQ[64 * 64];     // [quad][row] staged slab (64KB)
  __shared__ float redQ[2][64][17];                   // MFMA k-half exchange (8.7KB)
  __shared__ __align__(16) uint4 hrowQ[64];
  __shared__ __align__(16) uint4 qrowQ[32];
  __shared__ __align__(8)  _Float16 outH[512];        // [64 rows][8 cols]
  __shared__ __align__(8)  _Float16 giH[512];
  __shared__ float bp1L[PHn], bp2L[2 * Dn], pL[2 * Dn];
  __shared__ float xrowL[Dn], mrowL[Dn];
  __shared__ float bclfL[CLFHn], wclf2L[CLFHn], bgL[48];
  __shared__ float obsL[64];

  unsigned long long* outU = (unsigned long long*)outH;
  unsigned long long* giU  = (unsigned long long*)giH;

  auto slabp = [&](int arr, int buf) -> uint4* {
    return (uint4*)(a.act + ((size_t)(arr * 4 + buf) << 18));
  };

  // ---- h0 for block's 64 rows x 8 cols (redQ/stageQ as f32 scratch) ----
  float hfull;
  {
    float* covF = (float*)redQ;              // [64][32] f32 (8KB)
    float* midF = (float*)stageQ;            // [64][128] f32 (32KB)
    for (int i = tid; i < 64 * 32; i += NT)
      covF[i] = a.cov[(size_t)rgofs * COVn + i];
    __syncthreads();
    for (int i = tid; i < 64 * 128; i += NT) {
      const int rr = i >> 7, m = i & 127;
      float acc = a.bc1[m];
      #pragma unroll 8
      for (int k = 0; k < COVn; ++k) acc += covF[rr * 32 + k] * a.Wc1[m * COVn + k];
      midF[i] = fmaxf(acc, 0.0f);
    }
    __syncthreads();
    {
      float acc = a.bc2[c];
      const float* w2 = a.Wc2 + (size_t)c * COVHn;
      #pragma unroll 4
      for (int k = 0; k < COVHn; ++k) acc += midF[r_loc * 128 + k] * w2[k];
      hfull = tanhf(acc);
      outH[r_loc * 8 + c_loc] = (_Float16)hfull;
    }
    __syncthreads();
    unsigned long long* hA3u = (unsigned long long*)slabp(0, 3);
    const size_t oub0 = (size_t)(cg * 256 + rgofs) * 2;
    if (tid < 128) cohS(&hA3u[oub0 + tid], outU[tid]);
    __syncthreads();
  }

  // ---- one-time: pack owned weight rows f32 -> f16 quads in LDS ----
  for (int nfo = tid; nfo < 4608; nfo += NT) {
    int li; const float* srow; uint4* dst;
    if (nfo < 3072) {
      li = nfo & 1023; const int seg = nfo >> 10;
      const int n = li >> 6;
      const int col = cg * 8 + (n & 7);
      if (seg == 0)      { srow = (n < 8 ? a.Whr : a.Whz) + (size_t)col * Hn; dst = Wrz16; }
      else if (seg == 1) { srow = a.W_ih + (size_t)((n < 8 ? 0 : Hn) + col) * Hn; dst = Wxrz16; }
      else               { srow = a.W_hh + (size_t)((n < 8 ? 0 : Hn) + col) * Hn; dst = Whrz16; }
    } else {
      li = (nfo - 3072) & 511; const int seg = (nfo - 3072) >> 9;
      const int n = li >> 6; const int col = cg * 8 + n;
      if (seg == 0)      { srow = a.Whh + (size_t)col * Hn; dst = Whh8; }
      else if (seg == 1) { srow = a.W_ih + (size_t)(2 * Hn + col) * Hn; dst = Wxn8; }
      else               { srow = a.W_hh + (size_t)(2 * Hn + col) * Hn; dst = Whn8; }
    }
    const int q = li & 63;
    const float* s8 = srow + q * 8;
    uint4 u;
    u.x = pack2(s8[0], s8[1]); u.y = pack2(s8[2], s8[3]);
    u.z = pack2(s8[4], s8[5]); u.w = pack2(s8[6], s8[7]);
    dst[li] = u;
  }
  if (tid < PHn)    bp1L[tid] = a.bp1[tid];
  if (tid < 2 * Dn) bp2L[tid] = a.bp2[tid];
  if (tid < CLFHn)  { bclfL[tid] = a.bclf1[tid]; wclf2L[tid] = a.Wclf2[tid]; }
  if (tid < 48) {
    const int cl = tid / 6, rem = tid % 6, gate = rem >> 1, s = rem & 1;
    const int j = gate * Hn + cg * 8 + cl;
    bgL[tid] = s ? a.b_hh[j] : a.b_ih[j];
  }
  const float bclf2r = a.bclf2[0];

  unsigned ep = 0;
  bar_arrive(a.bar, line); bar_wait(a.bar, rg, ep);

  float zz = 0.f, hbc = 0.f;
  const size_t oub = (size_t)(cg * 256 + rgofs) * 2;   // u64 base of block's slab region

  // cached stage of cohort's 64 rows of a slab into stageQ ([quad][row] uint4)
  auto stage_fill = [&](const uint4* A) {
    #pragma unroll
    for (int i = 0; i < 8; ++i) {
      const int idx = tid + i * NT;              // 0..4095 = quad*64 + row
      stageQ[idx] = A[(size_t)(idx >> 6) * 256 + rgofs + (idx & 63)];
    }
  };

  // ---- MFMA engines: Y[64x16] = stage[64x512] x B^T, waves = (mtile, khalf) ----
  auto ldA = [&](int ks) -> f16x8 {
    return __builtin_bit_cast(f16x8,
        stageQ[(4 * ks + (lane >> 4)) * 64 + mt * 16 + (lane & 15)]);
  };
  auto mma_wide = [&](const uint4* Bw) -> f32x4 {
    f32x4 acc = {0.f, 0.f, 0.f, 0.f};
    #pragma unroll
    for (int i = 0; i < 8; ++i) {
      const int ks = kh * 8 + i;
      const f16x8 bv = __builtin_bit_cast(f16x8, Bw[(lane & 15) * 64 + ks * 4 + (lane >> 4)]);
      acc = __builtin_amdgcn_mfma_f32_16x16x32_f16(ldA(ks), bv, acc, 0, 0, 0);
    }
    return acc;
  };
  auto mma_half = [&](const uint4* Bw) -> f32x4 {
    f32x4 acc = {0.f, 0.f, 0.f, 0.f};
    const int n = lane & 15;
    #pragma unroll
    for (int i = 0; i < 8; ++i) {
      const int ks = kh * 8 + i;
      uint4 ub = {0u, 0u, 0u, 0u};
      if (n < 8) ub = Bw[n * 64 + ks * 4 + (lane >> 4)];
      acc = __builtin_amdgcn_mfma_f32_16x16x32_f16(ldA(ks), __builtin_bit_cast(f16x8, ub),
                                                   acc, 0, 0, 0);
    }
    return acc;
  };
  auto redw = [&](f32x4 acc) {
    const int col = lane & 15, r0 = mt * 16 + ((lane >> 4) << 2);
    #pragma unroll
    for (int j = 0; j < 4; ++j) redQ[kh][r0 + j][col] = acc[j];
  };

  auto do_clf = [&](const uint4* hAbase, int tout) {
    if (tid < CLFHn) {
      hrowQ[tid] = hAbase[(size_t)tid * 256 + g];
      float acc = bclfL[tid];
      #pragma unroll 8
      for (int q = 0; q < Hn / 8; ++q) acc = dotq(a.Wclf1Q[q * CLFHn + tid], hrowQ[q], acc);
      float cc = fmaxf(acc, 0.0f) * wclf2L[tid];
      #pragma unroll
      for (int o = 32; o; o >>= 1) cc += __shfl_down(cc, o, 64);
      if (tid == 0) a.out[tout * Bn + g] = cc + bclf2r;
    }
  };

  for (int t = 0; t < Tn; ++t) {
    if ((t & 3) == 0) __builtin_amdgcn_fence(__ATOMIC_ACQUIRE, "agent");

    const int bs = t & 3, bp = (t + 3) & 3;
    const uint4* hA_prev = slabp(0, bp);
    uint4* rh_cur = slabp(1, bs);
    uint4* hB_cur = slabp(2, bs);
    uint4* gi_cur = slabp(3, bs);
    uint4* hA_cur = slabp(0, bs);
    float* obs_cur = a.obs + bs * 256;

    // ---- P1: sr,sz via one paired MFMA pass; publish rh ----
    stage_fill(hA_prev);
    __syncthreads();
    redw(mma_wide(Wrz16));
    __syncthreads();
    {
      const float sr = redQ[0][r_loc][c_loc]     + redQ[1][r_loc][c_loc];
      const float sz = redQ[0][r_loc][c_loc + 8] + redQ[1][r_loc][c_loc + 8];
      const float rr = sigmoidf(sr);
      zz = sigmoidf(sz);
      outH[r_loc * 8 + c_loc] = (_Float16)(rr * hfull);
    }
    __syncthreads();
    if (tid < 128) cohS(((unsigned long long*)rh_cur) + oub + tid, outU[tid]);
    bar_arrive(a.bar, line);
    if (t > 0) do_clf(hA_prev, t - 1);          // hides b1 wait
    bar_wait(a.bar, rg, ep);

    // ---- P2: su via half pass; Euler; publish hB ----
    stage_fill(rh_cur);
    __syncthreads();
    redw(mma_half(Whh8));
    __syncthreads();
    {
      const float su = redQ[0][r_loc][c_loc] + redQ[1][r_loc][c_loc];
      const float u = tanhf(su);
      hbc = hfull + DTc * (1.0f - zz) * (u - hfull);
      outH[r_loc * 8 + c_loc] = (_Float16)hbc;
    }
    __syncthreads();
    if (tid < 128) cohS(((unsigned long long*)hB_cur) + oub + tid, outU[tid]);
    bar_arrive(a.bar, line);
    if (tid >= 64 && tid < 96)        xrowL[tid - 64] = a.X[((size_t)t * Bn + g) * Dn + (tid - 64)];
    else if (tid >= 96 && tid < 128)  mrowL[tid - 96] = a.M[((size_t)t * Bn + g) * Dn + (tid - 96)];
    bar_wait(a.bar, rg, ep);

    // ---- P3 (duty row g): q -> p -> prep -> gi, obs (VALU path) ----
    if (tid < 64) hrowQ[tid] = hB_cur[(size_t)tid * 256 + g];
    __syncthreads();
    if (tid < PHn) {
      float a0 = bp1L[tid], a1 = 0.f;
      #pragma unroll 8
      for (int q = 0; q < Hn / 8; q += 2) {
        a0 = dotq(a.Wp1Q[q * PHn + tid], hrowQ[q], a0);
        a1 = dotq(a.Wp1Q[(q + 1) * PHn + tid], hrowQ[q + 1], a1);
      }
      ((_Float16*)qrowQ)[tid] = (_Float16)fmaxf(a0 + a1, 0.0f);
    }
    __syncthreads();
    if (tid < 2 * Dn) {
      float acc = bp2L[tid];
      #pragma unroll 4
      for (int q = 0; q < PHn / 8; ++q)
        acc = dotq(a.Wp2Q[q * (2 * Dn) + tid], qrowQ[q], acc);
      pL[tid] = acc;
    }
    __syncthreads();
    {
      const int d = tid >> 4, pp = tid & 15;
      const float xv   = xrowL[d];
      const float mean = pL[d];
      const float logv = pL[Dn + d];
      const float err  = (xv - mean) * __expf(-0.5f * logv);
      float acc = a.bias_prep[d * PREPn + pp];
      acc += xv   * a.w_prep[(d * 4 + 0) * PREPn + pp];
      acc += mean * a.w_prep[(d * 4 + 1) * PREPn + pp];
      acc += logv * a.w_prep[(d * 4 + 2) * PREPn + pp];
      acc += err  * a.w_prep[(d * 4 + 3) * PREPn + pp];
      giH[tid] = (_Float16)(fmaxf(acc, 0.0f) * mrowL[d]);
      if (tid < 32) {
        const unsigned long long bb = __ballot(mrowL[tid] > 0.0f);
        if (tid == 0) cohSf(&obs_cur[g], bb ? 1.0f : 0.0f);
      }
    }
    __syncthreads();
    if (tid < 128)
      cohS(((unsigned long long*)gi_cur) + (size_t)(tid >> 1) * 512 + g * 2 + (tid & 1), giU[tid]);
    bar_arrive(a.bar, line);                       // b3 arrive EARLY

    // ---- P4 h-side hidden under b3: hB MFMA passes (r|z paired, n half) ----
    stage_fill(hB_cur);
    __syncthreads();
    redw(mma_wide(Whrz16));
    __syncthreads();
    const float hr = redQ[0][r_loc][c_loc]     + redQ[1][r_loc][c_loc];
    const float hz = redQ[0][r_loc][c_loc + 8] + redQ[1][r_loc][c_loc + 8];
    __syncthreads();                               // consumers done before redQ reuse
    redw(mma_half(Whn8));
    __syncthreads();
    const float hn = redQ[0][r_loc][c_loc] + redQ[1][r_loc][c_loc];
    bar_wait(a.bar, rg, ep);                       // cohort's gi now visible

    // ---- P4 x-side: gi MFMA passes; combine; publish hA ----
    stage_fill(gi_cur);
    if (tid < 64) obsL[tid] = obs_cur[rgofs + tid];
    __syncthreads();
    redw(mma_wide(Wxrz16));
    __syncthreads();
    const float xr = redQ[0][r_loc][c_loc]     + redQ[1][r_loc][c_loc];
    const float xz = redQ[0][r_loc][c_loc + 8] + redQ[1][r_loc][c_loc + 8];
    __syncthreads();
    redw(mma_half(Wxn8));
    __syncthreads();
    {
      const float xn  = redQ[0][r_loc][c_loc] + redQ[1][r_loc][c_loc];
      const float rgg = sigmoidf(xr + hr + bgL[c_loc * 6 + 0] + bgL[c_loc * 6 + 1]);
      const float zgg = sigmoidf(xz + hz + bgL[c_loc * 6 + 2] + bgL[c_loc * 6 + 3]);
      const float ng  = tanhf(xn + bgL[c_loc * 6 + 4] + rgg * (hn + bgL[c_loc * 6 + 5]));
      hfull = (obsL[r_loc] > 0.0f) ? ((1.0f - zgg) * ng + zgg * hbc) : hbc;
      outH[r_loc * 8 + c_loc] = (_Float16)hfull;
    }
    __syncthreads();
    if (tid < 128) cohS(((unsigned long long*)hA_cur) + oub + tid, outU[tid]);
    bar_arrive(a.bar, line);
    bar_wait(a.bar, rg, ep);
  }

  do_clf(slabp(0, (Tn - 1) & 3), Tn - 1);
}

extern "C" void kernel_launch(void* const* d_in, const int* in_sizes, int n_in,
                              void* d_out, int out_size, void* d_ws, size_t ws_size,
                              hipStream_t stream) {
  char* ws = (char*)d_ws;

  CoopArgs a;
  a.cov  = (const float*)d_in[0];
  a.X    = (const float*)d_in[1];
  a.M    = (const float*)d_in[2];
  a.Wc1  = (const float*)d_in[3];  a.bc1 = (const float*)d_in[4];
  a.Wc2  = (const float*)d_in[5];  a.bc2 = (const float*)d_in[6];
  a.Whr  = (const float*)d_in[7];  a.Whz = (const float*)d_in[8];  a.Whh = (const float*)d_in[9];
  const float* Wp1 = (const float*)d_in[10]; a.bp1 = (const float*)d_in[11];
  const float* Wp2 = (const float*)d_in[12]; a.bp2 = (const float*)d_in[13];
  a.w_prep = (const float*)d_in[14]; a.bias_prep = (const float*)d_in[15];
  a.W_ih = (const float*)d_in[16]; a.W_hh = (const float*)d_in[17];
  a.b_ih = (const float*)d_in[18]; a.b_hh = (const float*)d_in[19];
  const float* Wclf1 = (const float*)d_in[20]; a.bclf1 = (const float*)d_in[21];
  a.Wclf2 = (const float*)d_in[22]; a.bclf2 = (const float*)d_in[23];

  _Float16* pk = (_Float16*)ws;
  a.Wp1Q   = (const uint4*)(pk + PK_WP1);
  a.Wp2Q   = (const uint4*)(pk + PK_WP2);
  a.Wclf1Q = (const uint4*)(pk + PK_WCLF1);
  a.act = ws + WS_ACT;
  a.obs = (float*)(ws + WS_OBS);
  a.bar = (unsigned*)(ws + WS_BAR);
  a.out = (float*)d_out;

  PrepArgs p;
  p.Wp1 = Wp1; p.Wp2 = Wp2; p.Wclf1 = Wclf1;
  p.dst = pk; p.bar = a.bar;
  prep_pack_kernel<<<(PK_TOTAL + 255) / 256, 256, 0, stream>>>(p);
  gruode_coop<<<Bn, NT, 0, stream>>>(a);
}

// Round 10
// 5172.370 us; speedup vs baseline: 4.9540x; 1.0999x over previous
//
#include <hip/hip_runtime.h>
#include <hip/hip_bf16.h>

// Problem constants
constexpr int Bn = 256, Tn = 200, Dn = 32, Hn = 512, PHn = 256, PREPn = 16;
constexpr int COVn = 32, COVHn = 128, CLFHn = 64;
constexpr float DTc = 0.05f;
constexpr int NT = 512;
// grid = 256 blocks = 64 col-groups x 4 row-groups (1 block/CU, proven co-resident).
// block (cg,rg): owns H-cols [8cg,8cg+8) (= slab quad cg) x batch-rows [64rg,64rg+64);
// duty row g = rg*64+cg. 4 rg-cohorts of 64 blocks are independent (cohort barriers).

constexpr int CSTR = 32;               // barrier counter line stride in u32 (128B)
constexpr int NLINES = 64;             // 4 cohorts x 16 lines

typedef _Float16 h2v __attribute__((ext_vector_type(2)));
typedef _Float16 f16x8 __attribute__((ext_vector_type(8)));
typedef float f32x4 __attribute__((ext_vector_type(4)));

// packed f16 quad layout for streamed matrices: elem (k,j) of [N,K] at ((k>>3)*N + j)*8 + (k&7)
constexpr int PK_WP1   = 0;        // 256x512
constexpr int PK_WP2   = 131072;   // 64x256
constexpr int PK_WCLF1 = 147456;   // 64x512
constexpr int PK_TOTAL = 180224;

// ws byte offsets. Activation ring: 4 arrays (hA,rh,hB,gi) x 4 step-parity
// buffers, slab = f16 [64 quads][256 rows][8] = 256KB. Coherence: sys-scope
// writes (to L3) + cached reads + fence(acquire,agent) every 4 steps.
constexpr size_t WS_ACT = 393216;      // 16 x 262144 -> ends 4587520
constexpr size_t WS_OBS = 4587520;     // 4 bufs x 256 f32
constexpr size_t WS_BAR = 4591616;     // NLINES*CSTR u32, zeroed by prep

__device__ __forceinline__ float sigmoidf(float x) { return 1.0f / (1.0f + __expf(-x)); }

__device__ __forceinline__ float fdot2(unsigned w, unsigned v, float acc) {
#if __has_builtin(__builtin_amdgcn_fdot2)
  return __builtin_amdgcn_fdot2(__builtin_bit_cast(h2v, w),
                                __builtin_bit_cast(h2v, v), acc, false);
#else
  h2v a = __builtin_bit_cast(h2v, w), b = __builtin_bit_cast(h2v, v);
  return acc + (float)a.x * (float)b.x + (float)a.y * (float)b.y;
#endif
}
__device__ __forceinline__ float dotq(uint4 w, uint4 h, float acc) {
  acc = fdot2(w.x, h.x, acc); acc = fdot2(w.y, h.y, acc);
  acc = fdot2(w.z, h.z, acc); acc = fdot2(w.w, h.w, acc);
  return acc;
}
__device__ __forceinline__ unsigned pack2(float a, float b) {
  h2v h; h.x = (_Float16)a; h.y = (_Float16)b;
  return __builtin_bit_cast(unsigned, h);
}

// system-scope (L2-bypass) stores for cross-block activation writes
__device__ __forceinline__ void cohS(unsigned long long* p, unsigned long long v) {
  __hip_atomic_store(p, v, __ATOMIC_RELAXED, __HIP_MEMORY_SCOPE_SYSTEM);
}
__device__ __forceinline__ void cohSf(float* p, float v) {
  __hip_atomic_store(p, v, __ATOMIC_RELAXED, __HIP_MEMORY_SCOPE_SYSTEM);
}

// ---- fence-free distributed COHORT barrier (64 blocks; 16 lines per cohort) ----
__device__ __forceinline__ void bar_arrive(unsigned* ctrs, int line) {
  __syncthreads();   // drains vmcnt: sys-scope stores reached L3 before bump
  if (threadIdx.x == 0)
    __hip_atomic_fetch_add(&ctrs[line * CSTR], 1u,
                           __ATOMIC_RELAXED, __HIP_MEMORY_SCOPE_AGENT);
}
__device__ __forceinline__ void bar_wait(unsigned* ctrs, int rg, unsigned& ep) {
  ep += 1;
  const unsigned target = ep * 64u;
  if (threadIdx.x < 16) {
    const unsigned* myc = &ctrs[(rg * 16 + threadIdx.x) * CSTR];
    for (;;) {
      unsigned s = __hip_atomic_load(myc, __ATOMIC_RELAXED, __HIP_MEMORY_SCOPE_AGENT);
      #pragma unroll
      for (int o = 8; o; o >>= 1) s += __shfl_down(s, o, 16);
      s = __shfl(s, 0, 16);
      if (s >= target) break;
      __builtin_amdgcn_s_sleep(1);
    }
  }
  __syncthreads();
}

// ---------------- prep: pack Wp1/Wp2/Wclf1 to f16 quads; zero barrier counters ----------------
struct PrepArgs { const float *Wp1, *Wp2, *Wclf1; _Float16* dst; unsigned* bar; };

__global__ void prep_pack_kernel(PrepArgs a) {
  const int idx = blockIdx.x * 256 + threadIdx.x;
  if (idx < NLINES * CSTR) a.bar[idx] = 0u;
  if (idx >= PK_TOTAL) return;
  int off, N, K; const float* src;
  if      (idx < PK_WP2)   { off = PK_WP1;   N = 256; K = 512; src = a.Wp1; }
  else if (idx < PK_WCLF1) { off = PK_WP2;   N = 64;  K = 256; src = a.Wp2; }
  else                     { off = PK_WCLF1; N = 64;  K = 512; src = a.Wclf1; }
  const int li = idx - off, e = li & 7, t2 = li >> 3, j = t2 % N, k8 = t2 / N;
  a.dst[idx] = (_Float16)src[(size_t)j * K + k8 * 8 + e];
}

// ---------------- main persistent kernel ----------------
struct CoopArgs {
  const float *cov, *X, *M;
  const float *Wc1, *bc1, *Wc2, *bc2;
  const float *Whr, *Whz, *Whh;
  const float *bp1, *bp2;
  const float *w_prep, *bias_prep;
  const float *W_ih, *W_hh, *b_ih, *b_hh;
  const float *bclf1, *Wclf2, *bclf2;
  const uint4 *Wp1Q, *Wp2Q, *Wclf1Q;
  char* act;          // 16 slabs base
  float* obs;         // 4 x 256
  unsigned* bar;
  float* out;
};

__global__ __launch_bounds__(NT)
void gruode_coop(CoopArgs a) {
  const int bid = blockIdx.x, tid = threadIdx.x;
  const int cg = bid >> 2, rg = bid & 3;
  const int g = rg * 64 + cg;                  // duty row (inside own cohort's rows)
  const int c_loc = tid >> 6, r_loc = tid & 63;
  const int c = cg * 8 + c_loc;
  const int lane = tid & 63, wv = tid >> 6;
  const int mt = wv & 3, kh = wv >> 2;         // (mtile, khalf) roles for P1/P2
  const int pp4 = wv >> 2;                     // (mtile, pass) roles for P4
  const int line = rg * 16 + (cg & 15);
  const int rgofs = rg * 64;

  // LDS. B-operand weights in conflict-free [quad][padded-col] layouts:
  // wide (16 cols) stride 17; half (8 cols) stride 9 -> group bank bases rotate.
  __shared__ __align__(16) uint4 Wrz16[64 * 17];      // Whr|Whz paired (17KB)
  __shared__ __align__(16) uint4 Wxrz16[64 * 17];     // W_ih r|z
  __shared__ __align__(16) uint4 Whrz16[64 * 17];     // W_hh r|z
  __shared__ __align__(16) uint4 Whh8[64 * 9];        // Whh (9KB)
  __shared__ __align__(16) uint4 Wxn8[64 * 9];        // W_ih n
  __shared__ __align__(16) uint4 Whn8[64 * 9];        // W_hh n
  __shared__ __align__(16) uint4 stageQ[64 * 64];     // [quad][row] staged slab (64KB)
  __shared__ float redQ[2][64][17];                   // MFMA exchange (8.7KB)
  __shared__ __align__(16) uint4 hrowQ[64];
  __shared__ __align__(16) uint4 qrowQ[32];
  __shared__ __align__(8)  _Float16 outH[512];        // [64 rows][8 cols]
  __shared__ __align__(8)  _Float16 giH[512];
  __shared__ float bp1L[PHn], bp2L[2 * Dn], pL[2 * Dn];
  __shared__ float xrowL[Dn], mrowL[Dn];
  __shared__ float bclfL[CLFHn], wclf2L[CLFHn], bgL[48];
  __shared__ float obsL[64];

  unsigned long long* outU = (unsigned long long*)outH;
  unsigned long long* giU  = (unsigned long long*)giH;

  auto slabp = [&](int arr, int buf) -> uint4* {
    return (uint4*)(a.act + ((size_t)(arr * 4 + buf) << 18));
  };

  // ---- h0 for block's 64 rows x 8 cols (redQ/stageQ as f32 scratch) ----
  float hfull;
  {
    float* covF = (float*)redQ;              // [64][32] f32 (8KB of 8.7KB)
    float* midF = (float*)stageQ;            // [64][128] f32 (32KB of 64KB)
    for (int i = tid; i < 64 * 32; i += NT)
      covF[i] = a.cov[(size_t)rgofs * COVn + i];
    __syncthreads();
    for (int i = tid; i < 64 * 128; i += NT) {
      const int rr = i >> 7, m = i & 127;
      float acc = a.bc1[m];
      #pragma unroll 8
      for (int k = 0; k < COVn; ++k) acc += covF[rr * 32 + k] * a.Wc1[m * COVn + k];
      midF[i] = fmaxf(acc, 0.0f);
    }
    __syncthreads();
    {
      float acc = a.bc2[c];
      const float* w2 = a.Wc2 + (size_t)c * COVHn;
      #pragma unroll 4
      for (int k = 0; k < COVHn; ++k) acc += midF[r_loc * 128 + k] * w2[k];
      hfull = tanhf(acc);
      outH[r_loc * 8 + c_loc] = (_Float16)hfull;
    }
    __syncthreads();
    unsigned long long* hA3u = (unsigned long long*)slabp(0, 3);
    const size_t oub0 = (size_t)(cg * 256 + rgofs) * 2;
    if (tid < 128) cohS(&hA3u[oub0 + tid], outU[tid]);
    __syncthreads();
  }

  // ---- one-time: pack owned weight rows f32 -> f16 quads in LDS ----
  // wide: dst[q*17 + n] (n<16); half: dst[q*9 + n] (n<8)
  for (int nfo = tid; nfo < 4608; nfo += NT) {
    int li; const float* srow; uint4* dst; int phys;
    if (nfo < 3072) {
      li = nfo & 1023; const int seg = nfo >> 10;
      const int n = li >> 6, q = li & 63;
      const int col = cg * 8 + (n & 7);
      if (seg == 0)      { srow = (n < 8 ? a.Whr : a.Whz) + (size_t)col * Hn; dst = Wrz16; }
      else if (seg == 1) { srow = a.W_ih + (size_t)((n < 8 ? 0 : Hn) + col) * Hn; dst = Wxrz16; }
      else               { srow = a.W_hh + (size_t)((n < 8 ? 0 : Hn) + col) * Hn; dst = Whrz16; }
      phys = q * 17 + n;
      const float* s8 = srow + q * 8;
      uint4 u;
      u.x = pack2(s8[0], s8[1]); u.y = pack2(s8[2], s8[3]);
      u.z = pack2(s8[4], s8[5]); u.w = pack2(s8[6], s8[7]);
      dst[phys] = u;
    } else {
      li = (nfo - 3072) & 511; const int seg = (nfo - 3072) >> 9;
      const int n = li >> 6, q = li & 63;
      const int col = cg * 8 + n;
      if (seg == 0)      { srow = a.Whh + (size_t)col * Hn; dst = Whh8; }
      else if (seg == 1) { srow = a.W_ih + (size_t)(2 * Hn + col) * Hn; dst = Wxn8; }
      else               { srow = a.W_hh + (size_t)(2 * Hn + col) * Hn; dst = Whn8; }
      phys = q * 9 + n;
      const float* s8 = srow + q * 8;
      uint4 u;
      u.x = pack2(s8[0], s8[1]); u.y = pack2(s8[2], s8[3]);
      u.z = pack2(s8[4], s8[5]); u.w = pack2(s8[6], s8[7]);
      dst[phys] = u;
    }
  }
  if (tid < PHn)    bp1L[tid] = a.bp1[tid];
  if (tid < 2 * Dn) bp2L[tid] = a.bp2[tid];
  if (tid < CLFHn)  { bclfL[tid] = a.bclf1[tid]; wclf2L[tid] = a.Wclf2[tid]; }
  if (tid < 48) {
    const int cl = tid / 6, rem = tid % 6, gate = rem >> 1, s = rem & 1;
    const int j = gate * Hn + cg * 8 + cl;
    bgL[tid] = s ? a.b_hh[j] : a.b_ih[j];
  }
  const float bclf2r = a.bclf2[0];

  unsigned ep = 0;
  bar_arrive(a.bar, line); bar_wait(a.bar, rg, ep);

  float zz = 0.f, hbc = 0.f;
  const size_t oub = (size_t)(cg * 256 + rgofs) * 2;   // u64 base of block's slab region

  // cached stage of cohort's 64 rows of a slab into stageQ ([quad][row] uint4)
  auto stage_fill = [&](const uint4* A) {
    #pragma unroll
    for (int i = 0; i < 8; ++i) {
      const int idx = tid + i * NT;              // 0..4095 = quad*64 + row
      stageQ[idx] = A[(size_t)(idx >> 6) * 256 + rgofs + (idx & 63)];
    }
  };

  // ---- MFMA engines ----
  auto ldA = [&](int ks) -> f16x8 {
    return __builtin_bit_cast(f16x8,
        stageQ[(4 * ks + (lane >> 4)) * 64 + mt * 16 + (lane & 15)]);
  };
  // (mt,kh) roles: K split in halves, redQ[kh] sum
  auto mma_wide = [&](const uint4* Bw) -> f32x4 {
    f32x4 acc = {0.f, 0.f, 0.f, 0.f};
    const int n = lane & 15, l4 = lane >> 4;
    #pragma unroll
    for (int i = 0; i < 8; ++i) {
      const int ks = kh * 8 + i;
      const f16x8 bv = __builtin_bit_cast(f16x8, Bw[(ks * 4 + l4) * 17 + n]);
      acc = __builtin_amdgcn_mfma_f32_16x16x32_f16(ldA(ks), bv, acc, 0, 0, 0);
    }
    return acc;
  };
  auto mma_half = [&](const uint4* Bw) -> f32x4 {
    f32x4 acc = {0.f, 0.f, 0.f, 0.f};
    const int n = lane & 15, l4 = lane >> 4;
    #pragma unroll
    for (int i = 0; i < 8; ++i) {
      const int ks = kh * 8 + i;
      uint4 ub = {0u, 0u, 0u, 0u};
      if (n < 8) ub = Bw[(ks * 4 + l4) * 9 + n];
      acc = __builtin_amdgcn_mfma_f32_16x16x32_f16(ldA(ks), __builtin_bit_cast(f16x8, ub),
                                                   acc, 0, 0, 0);
    }
    return acc;
  };
  auto redw = [&](f32x4 acc) {
    const int col = lane & 15, r0 = mt * 16 + ((lane >> 4) << 2);
    #pragma unroll
    for (int j = 0; j < 4; ++j) redQ[kh][r0 + j][col] = acc[j];
  };
  // (mt,pass) roles for P4: p0 -> 16-col rz full-K -> redQ[0];
  //                         p1 -> 8-col n  full-K -> redQ[1]
  auto mma_p4 = [&](const uint4* Bw16, const uint4* Bw9) {
    f32x4 acc = {0.f, 0.f, 0.f, 0.f};
    const int n = lane & 15, l4 = lane >> 4;
    #pragma unroll
    for (int ks = 0; ks < 16; ++ks) {
      uint4 ub = {0u, 0u, 0u, 0u};
      if (pp4 == 0)      ub = Bw16[(ks * 4 + l4) * 17 + n];
      else if (n < 8)    ub = Bw9[(ks * 4 + l4) * 9 + n];
      acc = __builtin_amdgcn_mfma_f32_16x16x32_f16(ldA(ks), __builtin_bit_cast(f16x8, ub),
                                                   acc, 0, 0, 0);
    }
    const int col = lane & 15, r0 = mt * 16 + ((lane >> 4) << 2);
    #pragma unroll
    for (int j = 0; j < 4; ++j) redQ[pp4][r0 + j][col] = acc[j];
  };

  auto do_clf = [&](const uint4* hAbase, int tout) {
    if (tid < CLFHn) {
      hrowQ[tid] = hAbase[(size_t)tid * 256 + g];
      float acc = bclfL[tid];
      #pragma unroll 8
      for (int q = 0; q < Hn / 8; ++q) acc = dotq(a.Wclf1Q[q * CLFHn + tid], hrowQ[q], acc);
      float cc = fmaxf(acc, 0.0f) * wclf2L[tid];
      #pragma unroll
      for (int o = 32; o; o >>= 1) cc += __shfl_down(cc, o, 64);
      if (tid == 0) a.out[tout * Bn + g] = cc + bclf2r;
    }
  };

  for (int t = 0; t < Tn; ++t) {
    if ((t & 3) == 0) __builtin_amdgcn_fence(__ATOMIC_ACQUIRE, "agent");

    const int bs = t & 3, bp = (t + 3) & 3;
    const uint4* hA_prev = slabp(0, bp);
    uint4* rh_cur = slabp(1, bs);
    uint4* hB_cur = slabp(2, bs);
    uint4* gi_cur = slabp(3, bs);
    uint4* hA_cur = slabp(0, bs);
    float* obs_cur = a.obs + bs * 256;

    // ---- P1: sr,sz via paired wide pass (kh split); publish rh ----
    stage_fill(hA_prev);
    __syncthreads();
    redw(mma_wide(Wrz16));
    __syncthreads();
    {
      const float sr = redQ[0][r_loc][c_loc]     + redQ[1][r_loc][c_loc];
      const float sz = redQ[0][r_loc][c_loc + 8] + redQ[1][r_loc][c_loc + 8];
      const float rr = sigmoidf(sr);
      zz = sigmoidf(sz);
      outH[r_loc * 8 + c_loc] = (_Float16)(rr * hfull);
    }
    __syncthreads();
    if (tid < 128) cohS(((unsigned long long*)rh_cur) + oub + tid, outU[tid]);
    bar_arrive(a.bar, line);
    if (t > 0) do_clf(hA_prev, t - 1);          // hides b1 wait
    bar_wait(a.bar, rg, ep);

    // ---- P2: su via half pass (kh split); Euler; publish hB ----
    stage_fill(rh_cur);
    __syncthreads();
    redw(mma_half(Whh8));
    __syncthreads();
    {
      const float su = redQ[0][r_loc][c_loc] + redQ[1][r_loc][c_loc];
      const float u = tanhf(su);
      hbc = hfull + DTc * (1.0f - zz) * (u - hfull);
      outH[r_loc * 8 + c_loc] = (_Float16)hbc;
    }
    __syncthreads();
    if (tid < 128) cohS(((unsigned long long*)hB_cur) + oub + tid, outU[tid]);
    bar_arrive(a.bar, line);
    if (tid >= 64 && tid < 96)        xrowL[tid - 64] = a.X[((size_t)t * Bn + g) * Dn + (tid - 64)];
    else if (tid >= 96 && tid < 128)  mrowL[tid - 96] = a.M[((size_t)t * Bn + g) * Dn + (tid - 96)];
    bar_wait(a.bar, rg, ep);

    // ---- P3 (duty row g): q -> p -> prep -> gi, obs (VALU path) ----
    if (tid < 64) hrowQ[tid] = hB_cur[(size_t)tid * 256 + g];
    __syncthreads();
    if (tid < PHn) {
      float a0 = bp1L[tid], a1 = 0.f;
      #pragma unroll 8
      for (int q = 0; q < Hn / 8; q += 2) {
        a0 = dotq(a.Wp1Q[q * PHn + tid], hrowQ[q], a0);
        a1 = dotq(a.Wp1Q[(q + 1) * PHn + tid], hrowQ[q + 1], a1);
      }
      ((_Float16*)qrowQ)[tid] = (_Float16)fmaxf(a0 + a1, 0.0f);
    }
    __syncthreads();
    if (tid < 2 * Dn) {
      float acc = bp2L[tid];
      #pragma unroll 4
      for (int q = 0; q < PHn / 8; ++q)
        acc = dotq(a.Wp2Q[q * (2 * Dn) + tid], qrowQ[q], acc);
      pL[tid] = acc;
    }
    __syncthreads();
    {
      const int d = tid >> 4, pp = tid & 15;
      const float xv   = xrowL[d];
      const float mean = pL[d];
      const float logv = pL[Dn + d];
      const float err  = (xv - mean) * __expf(-0.5f * logv);
      float acc = a.bias_prep[d * PREPn + pp];
      acc += xv   * a.w_prep[(d * 4 + 0) * PREPn + pp];
      acc += mean * a.w_prep[(d * 4 + 1) * PREPn + pp];
      acc += logv * a.w_prep[(d * 4 + 2) * PREPn + pp];
      acc += err  * a.w_prep[(d * 4 + 3) * PREPn + pp];
      giH[tid] = (_Float16)(fmaxf(acc, 0.0f) * mrowL[d]);
      if (tid < 32) {
        const unsigned long long bb = __ballot(mrowL[tid] > 0.0f);
        if (tid == 0) cohSf(&obs_cur[g], bb ? 1.0f : 0.0f);
      }
    }
    __syncthreads();
    if (tid < 128)
      cohS(((unsigned long long*)gi_cur) + (size_t)(tid >> 1) * 512 + g * 2 + (tid & 1), giU[tid]);
    bar_arrive(a.bar, line);                       // b3 arrive EARLY

    // ---- P4 h-side hidden under b3: one combined (mt,pass) MFMA step over hB ----
    stage_fill(hB_cur);
    __syncthreads();
    mma_p4(Whrz16, Whn8);
    __syncthreads();
    const float hr = redQ[0][r_loc][c_loc];
    const float hz = redQ[0][r_loc][c_loc + 8];
    const float hn = redQ[1][r_loc][c_loc];
    bar_wait(a.bar, rg, ep);                       // cohort's gi now visible

    // ---- P4 x-side: combined (mt,pass) MFMA over gi; combine; publish hA ----
    stage_fill(gi_cur);
    if (tid < 64) obsL[tid] = obs_cur[rgofs + tid];
    __syncthreads();
    mma_p4(Wxrz16, Wxn8);
    __syncthreads();
    {
      const float xr = redQ[0][r_loc][c_loc];
      const float xz = redQ[0][r_loc][c_loc + 8];
      const float xn = redQ[1][r_loc][c_loc];
      const float rgg = sigmoidf(xr + hr + bgL[c_loc * 6 + 0] + bgL[c_loc * 6 + 1]);
      const float zgg = sigmoidf(xz + hz + bgL[c_loc * 6 + 2] + bgL[c_loc * 6 + 3]);
      const float ng  = tanhf(xn + bgL[c_loc * 6 + 4] + rgg * (hn + bgL[c_loc * 6 + 5]));
      hfull = (obsL[r_loc] > 0.0f) ? ((1.0f - zgg) * ng + zgg * hbc) : hbc;
      outH[r_loc * 8 + c_loc] = (_Float16)hfull;
    }
    __syncthreads();
    if (tid < 128) cohS(((unsigned long long*)hA_cur) + oub + tid, outU[tid]);
    bar_arrive(a.bar, line);
    bar_wait(a.bar, rg, ep);
  }

  do_clf(slabp(0, (Tn - 1) & 3), Tn - 1);
}

extern "C" void kernel_launch(void* const* d_in, const int* in_sizes, int n_in,
                              void* d_out, int out_size, void* d_ws, size_t ws_size,
                              hipStream_t stream) {
  char* ws = (char*)d_ws;

  CoopArgs a;
  a.cov  = (const float*)d_in[0];
  a.X    = (const float*)d_in[1];
  a.M    = (const float*)d_in[2];
  a.Wc1  = (const float*)d_in[3];  a.bc1 = (const float*)d_in[4];
  a.Wc2  = (const float*)d_in[5];  a.bc2 = (const float*)d_in[6];
  a.Whr  = (const float*)d_in[7];  a.Whz = (const float*)d_in[8];  a.Whh = (const float*)d_in[9];
  const float* Wp1 = (const float*)d_in[10]; a.bp1 = (const float*)d_in[11];
  const float* Wp2 = (const float*)d_in[12]; a.bp2 = (const float*)d_in[13];
  a.w_prep = (const float*)d_in[14]; a.bias_prep = (const float*)d_in[15];
  a.W_ih = (const float*)d_in[16]; a.W_hh = (const float*)d_in[17];
  a.b_ih = (const float*)d_in[18]; a.b_hh = (const float*)d_in[19];
  const float* Wclf1 = (const float*)d_in[20]; a.bclf1 = (const float*)d_in[21];
  a.Wclf2 = (const float*)d_in[22]; a.bclf2 = (const float*)d_in[23];

  _Float16* pk = (_Float16*)ws;
  a.Wp1Q   = (const uint4*)(pk + PK_WP1);
  a.Wp2Q   = (const uint4*)(pk + PK_WP2);
  a.Wclf1Q = (const uint4*)(pk + PK_WCLF1);
  a.act = ws + WS_ACT;
  a.obs = (float*)(ws + WS_OBS);
  a.bar = (unsigned*)(ws + WS_BAR);
  a.out = (float*)d_out;

  PrepArgs p;
  p.Wp1 = Wp1; p.Wp2 = Wp2; p.Wclf1 = Wclf1;
  p.dst = pk; p.bar = a.bar;
  prep_pack_kernel<<<(PK_TOTAL + 255) / 256, 256, 0, stream>>>(p);
  gruode_coop<<<Bn, NT, 0, stream>>>(a);
}

// Round 11
// 5116.772 us; speedup vs baseline: 5.0078x; 1.0109x over previous
//
#include <hip/hip_runtime.h>
#include <hip/hip_bf16.h>

// Problem constants
constexpr int Bn = 256, Tn = 200, Dn = 32, Hn = 512, PHn = 256, PREPn = 16;
constexpr int COVn = 32, COVHn = 128, CLFHn = 64;
constexpr float DTc = 0.05f;
constexpr int NT = 512;
// grid = 256 blocks = 64 col-groups x 4 row-groups (1 block/CU, proven co-resident).
// block (cg,rg): owns H-cols [8cg,8cg+8) (= slab quad cg) x batch-rows [64rg,64rg+64);
// duty row g = rg*64+cg. 4 rg-cohorts of 64 blocks are independent (cohort barriers).

constexpr int CSTR = 32;               // barrier counter line stride in u32 (128B)
constexpr int NLINES = 64;             // zeroed region (only 4 lines used now)

typedef _Float16 h2v __attribute__((ext_vector_type(2)));
typedef _Float16 f16x8 __attribute__((ext_vector_type(8)));
typedef float f32x4 __attribute__((ext_vector_type(4)));

// packed f16 quad layout for streamed matrices: elem (k,j) of [N,K] at ((k>>3)*N + j)*8 + (k&7)
constexpr int PK_WP1   = 0;        // 256x512
constexpr int PK_WP2   = 131072;   // 64x256
constexpr int PK_WCLF1 = 147456;   // 64x512
constexpr int PK_TOTAL = 180224;

// ws byte offsets. Activation ring: 4 arrays (hA,rh,hB,gi) x 4 step-parity
// buffers, slab = f16 [64 quads][256 rows][8] = 256KB. Coherence: sys-scope
// writes (to L3) + cached reads + fence(acquire,agent) every 4 steps.
constexpr size_t WS_ACT = 393216;      // 16 x 262144 -> ends 4587520
constexpr size_t WS_OBS = 4587520;     // 4 bufs x 256 f32
constexpr size_t WS_BAR = 4591616;     // NLINES*CSTR u32, zeroed by prep

__device__ __forceinline__ float sigmoidf(float x) { return 1.0f / (1.0f + __expf(-x)); }

__device__ __forceinline__ float fdot2(unsigned w, unsigned v, float acc) {
#if __has_builtin(__builtin_amdgcn_fdot2)
  return __builtin_amdgcn_fdot2(__builtin_bit_cast(h2v, w),
                                __builtin_bit_cast(h2v, v), acc, false);
#else
  h2v a = __builtin_bit_cast(h2v, w), b = __builtin_bit_cast(h2v, v);
  return acc + (float)a.x * (float)b.x + (float)a.y * (float)b.y;
#endif
}
__device__ __forceinline__ float dotq(uint4 w, uint4 h, float acc) {
  acc = fdot2(w.x, h.x, acc); acc = fdot2(w.y, h.y, acc);
  acc = fdot2(w.z, h.z, acc); acc = fdot2(w.w, h.w, acc);
  return acc;
}
__device__ __forceinline__ unsigned pack2(float a, float b) {
  h2v h; h.x = (_Float16)a; h.y = (_Float16)b;
  return __builtin_bit_cast(unsigned, h);
}

// system-scope (L2-bypass) stores for cross-block activation writes
__device__ __forceinline__ void cohS(unsigned long long* p, unsigned long long v) {
  __hip_atomic_store(p, v, __ATOMIC_RELAXED, __HIP_MEMORY_SCOPE_SYSTEM);
}
__device__ __forceinline__ void cohSf(float* p, float v) {
  __hip_atomic_store(p, v, __ATOMIC_RELAXED, __HIP_MEMORY_SCOPE_SYSTEM);
}

// ---- single-counter-per-cohort barrier (monotone; far-atomic arrivals) ----
__device__ __forceinline__ void bar_arrive(unsigned* ctrs, int rg) {
  __syncthreads();   // drains vmcnt: sys-scope stores reached L3 before bump
  if (threadIdx.x == 0)
    __hip_atomic_fetch_add(&ctrs[rg * CSTR], 1u,
                           __ATOMIC_RELAXED, __HIP_MEMORY_SCOPE_AGENT);
}
__device__ __forceinline__ void bar_wait(unsigned* ctrs, int rg, unsigned& ep) {
  ep += 1;
  const unsigned target = ep * 64u;
  if (threadIdx.x == 0) {
    const unsigned* myc = &ctrs[rg * CSTR];
    while (__hip_atomic_load(myc, __ATOMIC_RELAXED, __HIP_MEMORY_SCOPE_AGENT) < target)
      __builtin_amdgcn_s_sleep(1);
  }
  __syncthreads();
}

// ---------------- prep: pack Wp1/Wp2/Wclf1 to f16 quads; zero barrier counters ----------------
struct PrepArgs { const float *Wp1, *Wp2, *Wclf1; _Float16* dst; unsigned* bar; };

__global__ void prep_pack_kernel(PrepArgs a) {
  const int idx = blockIdx.x * 256 + threadIdx.x;
  if (idx < NLINES * CSTR) a.bar[idx] = 0u;
  if (idx >= PK_TOTAL) return;
  int off, N, K; const float* src;
  if      (idx < PK_WP2)   { off = PK_WP1;   N = 256; K = 512; src = a.Wp1; }
  else if (idx < PK_WCLF1) { off = PK_WP2;   N = 64;  K = 256; src = a.Wp2; }
  else                     { off = PK_WCLF1; N = 64;  K = 512; src = a.Wclf1; }
  const int li = idx - off, e = li & 7, t2 = li >> 3, j = t2 % N, k8 = t2 / N;
  a.dst[idx] = (_Float16)src[(size_t)j * K + k8 * 8 + e];
}

// ---------------- main persistent kernel ----------------
struct CoopArgs {
  const float *cov, *X, *M;
  const float *Wc1, *bc1, *Wc2, *bc2;
  const float *Whr, *Whz, *Whh;
  const float *bp1, *bp2;
  const float *w_prep, *bias_prep;
  const float *W_ih, *W_hh, *b_ih, *b_hh;
  const float *bclf1, *Wclf2, *bclf2;
  const uint4 *Wp1Q, *Wp2Q, *Wclf1Q;
  char* act;          // 16 slabs base
  float* obs;         // 4 x 256
  unsigned* bar;
  float* out;
};

__global__ __launch_bounds__(NT)
void gruode_coop(CoopArgs a) {
  const int bid = blockIdx.x, tid = threadIdx.x;
  const int cg = bid >> 2, rg = bid & 3;
  const int g = rg * 64 + cg;                  // duty row (inside own cohort's rows)
  const int c_loc = tid >> 6, r_loc = tid & 63;
  const int c = cg * 8 + c_loc;
  const int lane = tid & 63, wv = tid >> 6;
  const int mt = wv & 3, kh = wv >> 2;         // (mtile, khalf) roles for P1/P2
  const int pp4 = wv >> 2;                     // (mtile, pass) roles for P4
  const int rgofs = rg * 64;

  // LDS. B-operand weights in conflict-free [quad][padded-col] layouts:
  // wide (16 cols) stride 17; half (8 cols) stride 9 -> group bank bases rotate.
  __shared__ __align__(16) uint4 Wrz16[64 * 17];      // Whr|Whz paired (17KB)
  __shared__ __align__(16) uint4 Wxrz16[64 * 17];     // W_ih r|z
  __shared__ __align__(16) uint4 Whrz16[64 * 17];     // W_hh r|z
  __shared__ __align__(16) uint4 Whh8[64 * 9];        // Whh (9KB)
  __shared__ __align__(16) uint4 Wxn8[64 * 9];        // W_ih n
  __shared__ __align__(16) uint4 Whn8[64 * 9];        // W_hh n
  __shared__ __align__(16) uint4 stageQ[64 * 64];     // [quad][row] staged slab (64KB)
  __shared__ float redQ[2][64][17];                   // MFMA exchange (8.7KB)
  __shared__ __align__(16) uint4 hrowQ[64];
  __shared__ __align__(16) uint4 qrowQ[32];
  __shared__ __align__(8)  _Float16 outH[512];        // [64 rows][8 cols]
  __shared__ __align__(8)  _Float16 giH[512];
  __shared__ float bp1L[PHn], bp2L[2 * Dn], pL[2 * Dn];
  __shared__ float xrowL[Dn], mrowL[Dn];
  __shared__ float bclfL[CLFHn], wclf2L[CLFHn], bgL[48];
  __shared__ float obsL[64];

  unsigned long long* outU = (unsigned long long*)outH;
  unsigned long long* giU  = (unsigned long long*)giH;

  auto slabp = [&](int arr, int buf) -> uint4* {
    return (uint4*)(a.act + ((size_t)(arr * 4 + buf) << 18));
  };

  // ---- h0 for block's 64 rows x 8 cols (redQ/stageQ as f32 scratch) ----
  float hfull;
  {
    float* covF = (float*)redQ;              // [64][32] f32
    float* midF = (float*)stageQ;            // [64][128] f32
    for (int i = tid; i < 64 * 32; i += NT)
      covF[i] = a.cov[(size_t)rgofs * COVn + i];
    __syncthreads();
    for (int i = tid; i < 64 * 128; i += NT) {
      const int rr = i >> 7, m = i & 127;
      float acc = a.bc1[m];
      #pragma unroll 8
      for (int k = 0; k < COVn; ++k) acc += covF[rr * 32 + k] * a.Wc1[m * COVn + k];
      midF[i] = fmaxf(acc, 0.0f);
    }
    __syncthreads();
    {
      float acc = a.bc2[c];
      const float* w2 = a.Wc2 + (size_t)c * COVHn;
      #pragma unroll 4
      for (int k = 0; k < COVHn; ++k) acc += midF[r_loc * 128 + k] * w2[k];
      hfull = tanhf(acc);
      outH[r_loc * 8 + c_loc] = (_Float16)hfull;
    }
    __syncthreads();
    unsigned long long* hA3u = (unsigned long long*)slabp(0, 3);
    const size_t oub0 = (size_t)(cg * 256 + rgofs) * 2;
    if (tid < 128) cohS(&hA3u[oub0 + tid], outU[tid]);
    __syncthreads();
  }

  // ---- one-time: pack owned weight rows f32 -> f16 quads in LDS ----
  for (int nfo = tid; nfo < 4608; nfo += NT) {
    int li; const float* srow; uint4* dst; int phys;
    if (nfo < 3072) {
      li = nfo & 1023; const int seg = nfo >> 10;
      const int n = li >> 6, q = li & 63;
      const int col = cg * 8 + (n & 7);
      if (seg == 0)      { srow = (n < 8 ? a.Whr : a.Whz) + (size_t)col * Hn; dst = Wrz16; }
      else if (seg == 1) { srow = a.W_ih + (size_t)((n < 8 ? 0 : Hn) + col) * Hn; dst = Wxrz16; }
      else               { srow = a.W_hh + (size_t)((n < 8 ? 0 : Hn) + col) * Hn; dst = Whrz16; }
      phys = q * 17 + n;
      const float* s8 = srow + q * 8;
      uint4 u;
      u.x = pack2(s8[0], s8[1]); u.y = pack2(s8[2], s8[3]);
      u.z = pack2(s8[4], s8[5]); u.w = pack2(s8[6], s8[7]);
      dst[phys] = u;
    } else {
      li = (nfo - 3072) & 511; const int seg = (nfo - 3072) >> 9;
      const int n = li >> 6, q = li & 63;
      const int col = cg * 8 + n;
      if (seg == 0)      { srow = a.Whh + (size_t)col * Hn; dst = Whh8; }
      else if (seg == 1) { srow = a.W_ih + (size_t)(2 * Hn + col) * Hn; dst = Wxn8; }
      else               { srow = a.W_hh + (size_t)(2 * Hn + col) * Hn; dst = Whn8; }
      phys = q * 9 + n;
      const float* s8 = srow + q * 8;
      uint4 u;
      u.x = pack2(s8[0], s8[1]); u.y = pack2(s8[2], s8[3]);
      u.z = pack2(s8[4], s8[5]); u.w = pack2(s8[6], s8[7]);
      dst[phys] = u;
    }
  }
  if (tid < PHn)    bp1L[tid] = a.bp1[tid];
  if (tid < 2 * Dn) bp2L[tid] = a.bp2[tid];
  if (tid < CLFHn)  { bclfL[tid] = a.bclf1[tid]; wclf2L[tid] = a.Wclf2[tid]; }
  if (tid < 48) {
    const int cl = tid / 6, rem = tid % 6, gate = rem >> 1, s = rem & 1;
    const int j = gate * Hn + cg * 8 + cl;
    bgL[tid] = s ? a.b_hh[j] : a.b_ih[j];
  }
  // X/M preload for t = 0
  if (tid >= 64 && tid < 96)        xrowL[tid - 64] = a.X[(size_t)g * Dn + (tid - 64)];
  else if (tid >= 96 && tid < 128)  mrowL[tid - 96] = a.M[(size_t)g * Dn + (tid - 96)];
  const float bclf2r = a.bclf2[0];

  unsigned ep = 0;
  bar_arrive(a.bar, rg); bar_wait(a.bar, rg, ep);

  float zz = 0.f, hbc = 0.f;
  const size_t oub = (size_t)(cg * 256 + rgofs) * 2;   // u64 base of block's slab region

  // cached stage of cohort's 64 rows of a slab into stageQ ([quad][row] uint4)
  auto stage_fill = [&](const uint4* A) {
    #pragma unroll
    for (int i = 0; i < 8; ++i) {
      const int idx = tid + i * NT;              // 0..4095 = quad*64 + row
      stageQ[idx] = A[(size_t)(idx >> 6) * 256 + rgofs + (idx & 63)];
    }
  };

  // ---- MFMA engines ----
  auto ldA = [&](int ks) -> f16x8 {
    return __builtin_bit_cast(f16x8,
        stageQ[(4 * ks + (lane >> 4)) * 64 + mt * 16 + (lane & 15)]);
  };
  auto mma_wide = [&](const uint4* Bw) -> f32x4 {
    f32x4 acc = {0.f, 0.f, 0.f, 0.f};
    const int n = lane & 15, l4 = lane >> 4;
    #pragma unroll
    for (int i = 0; i < 8; ++i) {
      const int ks = kh * 8 + i;
      const f16x8 bv = __builtin_bit_cast(f16x8, Bw[(ks * 4 + l4) * 17 + n]);
      acc = __builtin_amdgcn_mfma_f32_16x16x32_f16(ldA(ks), bv, acc, 0, 0, 0);
    }
    return acc;
  };
  auto mma_half = [&](const uint4* Bw) -> f32x4 {
    f32x4 acc = {0.f, 0.f, 0.f, 0.f};
    const int n = lane & 15, l4 = lane >> 4;
    #pragma unroll
    for (int i = 0; i < 8; ++i) {
      const int ks = kh * 8 + i;
      uint4 ub = {0u, 0u, 0u, 0u};
      if (n < 8) ub = Bw[(ks * 4 + l4) * 9 + n];
      acc = __builtin_amdgcn_mfma_f32_16x16x32_f16(ldA(ks), __builtin_bit_cast(f16x8, ub),
                                                   acc, 0, 0, 0);
    }
    return acc;
  };
  auto redw = [&](f32x4 acc) {
    const int col = lane & 15, r0 = mt * 16 + ((lane >> 4) << 2);
    #pragma unroll
    for (int j = 0; j < 4; ++j) redQ[kh][r0 + j][col] = acc[j];
  };
  // (mt,pass) roles for P4: p0 -> 16-col rz full-K -> redQ[0];
  //                         p1 -> 8-col n  full-K -> redQ[1]
  auto mma_p4 = [&](const uint4* Bw16, const uint4* Bw9) {
    f32x4 acc = {0.f, 0.f, 0.f, 0.f};
    const int n = lane & 15, l4 = lane >> 4;
    #pragma unroll
    for (int ks = 0; ks < 16; ++ks) {
      uint4 ub = {0u, 0u, 0u, 0u};
      if (pp4 == 0)      ub = Bw16[(ks * 4 + l4) * 17 + n];
      else if (n < 8)    ub = Bw9[(ks * 4 + l4) * 9 + n];
      acc = __builtin_amdgcn_mfma_f32_16x16x32_f16(ldA(ks), __builtin_bit_cast(f16x8, ub),
                                                   acc, 0, 0, 0);
    }
    const int col = lane & 15, r0 = mt * 16 + ((lane >> 4) << 2);
    #pragma unroll
    for (int j = 0; j < 4; ++j) redQ[pp4][r0 + j][col] = acc[j];
  };

  auto do_clf = [&](const uint4* hAbase, int tout) {
    if (tid < CLFHn) {
      hrowQ[tid] = hAbase[(size_t)tid * 256 + g];
      float acc = bclfL[tid];
      #pragma unroll 8
      for (int q = 0; q < Hn / 8; ++q) acc = dotq(a.Wclf1Q[q * CLFHn + tid], hrowQ[q], acc);
      float cc = fmaxf(acc, 0.0f) * wclf2L[tid];
      #pragma unroll
      for (int o = 32; o; o >>= 1) cc += __shfl_down(cc, o, 64);
      if (tid == 0) a.out[tout * Bn + g] = cc + bclf2r;
    }
  };

  for (int t = 0; t < Tn; ++t) {
    if ((t & 3) == 0) __builtin_amdgcn_fence(__ATOMIC_ACQUIRE, "agent");

    const int bs = t & 3, bp = (t + 3) & 3;
    const uint4* hA_prev = slabp(0, bp);
    uint4* rh_cur = slabp(1, bs);
    uint4* hB_cur = slabp(2, bs);
    uint4* gi_cur = slabp(3, bs);
    uint4* hA_cur = slabp(0, bs);
    float* obs_cur = a.obs + bs * 256;

    // ---- P1: sr,sz via paired wide pass (kh split); publish rh ----
    stage_fill(hA_prev);
    __syncthreads();
    redw(mma_wide(Wrz16));
    __syncthreads();
    {
      const float sr = redQ[0][r_loc][c_loc]     + redQ[1][r_loc][c_loc];
      const float sz = redQ[0][r_loc][c_loc + 8] + redQ[1][r_loc][c_loc + 8];
      const float rr = sigmoidf(sr);
      zz = sigmoidf(sz);
      outH[r_loc * 8 + c_loc] = (_Float16)(rr * hfull);
    }
    __syncthreads();
    if (tid < 128) cohS(((unsigned long long*)rh_cur) + oub + tid, outU[tid]);
    bar_arrive(a.bar, rg);
    if (t > 0) do_clf(hA_prev, t - 1);          // hides b1 wait
    bar_wait(a.bar, rg, ep);

    // ---- P2: su via half pass (kh split); Euler; publish hB ----
    stage_fill(rh_cur);
    __syncthreads();
    redw(mma_half(Whh8));
    __syncthreads();
    {
      const float su = redQ[0][r_loc][c_loc] + redQ[1][r_loc][c_loc];
      const float u = tanhf(su);
      hbc = hfull + DTc * (1.0f - zz) * (u - hfull);
      outH[r_loc * 8 + c_loc] = (_Float16)hbc;
    }
    __syncthreads();
    if (tid < 128) cohS(((unsigned long long*)hB_cur) + oub + tid, outU[tid]);
    bar_arrive(a.bar, rg);
    bar_wait(a.bar, rg, ep);

    // ---- P3 (duty row g): q -> p -> prep -> gi, obs (VALU path) ----
    if (tid < 64) hrowQ[tid] = hB_cur[(size_t)tid * 256 + g];
    __syncthreads();
    if (tid < PHn) {
      float a0 = bp1L[tid], a1 = 0.f;
      #pragma unroll 8
      for (int q = 0; q < Hn / 8; q += 2) {
        a0 = dotq(a.Wp1Q[q * PHn + tid], hrowQ[q], a0);
        a1 = dotq(a.Wp1Q[(q + 1) * PHn + tid], hrowQ[q + 1], a1);
      }
      ((_Float16*)qrowQ)[tid] = (_Float16)fmaxf(a0 + a1, 0.0f);
    }
    __syncthreads();
    if (tid < 2 * Dn) {
      float acc = bp2L[tid];
      #pragma unroll 4
      for (int q = 0; q < PHn / 8; ++q)
        acc = dotq(a.Wp2Q[q * (2 * Dn) + tid], qrowQ[q], acc);
      pL[tid] = acc;
    }
    __syncthreads();
    {
      const int d = tid >> 4, pp = tid & 15;
      const float xv   = xrowL[d];
      const float mean = pL[d];
      const float logv = pL[Dn + d];
      const float err  = (xv - mean) * __expf(-0.5f * logv);
      float acc = a.bias_prep[d * PREPn + pp];
      acc += xv   * a.w_prep[(d * 4 + 0) * PREPn + pp];
      acc += mean * a.w_prep[(d * 4 + 1) * PREPn + pp];
      acc += logv * a.w_prep[(d * 4 + 2) * PREPn + pp];
      acc += err  * a.w_prep[(d * 4 + 3) * PREPn + pp];
      giH[tid] = (_Float16)(fmaxf(acc, 0.0f) * mrowL[d]);
      if (tid < 32) {
        const unsigned long long bb = __ballot(mrowL[tid] > 0.0f);
        if (tid == 0) cohSf(&obs_cur[g], bb ? 1.0f : 0.0f);
      }
    }
    __syncthreads();
    if (tid < 128)
      cohS(((unsigned long long*)gi_cur) + (size_t)(tid >> 1) * 512 + g * 2 + (tid & 1), giU[tid]);
    bar_arrive(a.bar, rg);                         // b3 arrive EARLY

    // ---- P4 h-side hidden under b3: one combined (mt,pass) MFMA step over hB ----
    stage_fill(hB_cur);
    __syncthreads();
    mma_p4(Whrz16, Whn8);
    __syncthreads();
    const float hr = redQ[0][r_loc][c_loc];
    const float hz = redQ[0][r_loc][c_loc + 8];
    const float hn = redQ[1][r_loc][c_loc];
    bar_wait(a.bar, rg, ep);                       // cohort's gi now visible

    // ---- P4 x-side: combined (mt,pass) MFMA over gi; combine; publish hA ----
    stage_fill(gi_cur);
    if (tid < 64) obsL[tid] = obs_cur[rgofs + tid];
    __syncthreads();
    mma_p4(Wxrz16, Wxn8);
    __syncthreads();
    {
      const float xr = redQ[0][r_loc][c_loc];
      const float xz = redQ[0][r_loc][c_loc + 8];
      const float xn = redQ[1][r_loc][c_loc];
      const float rgg = sigmoidf(xr + hr + bgL[c_loc * 6 + 0] + bgL[c_loc * 6 + 1]);
      const float zgg = sigmoidf(xz + hz + bgL[c_loc * 6 + 2] + bgL[c_loc * 6 + 3]);
      const float ng  = tanhf(xn + bgL[c_loc * 6 + 4] + rgg * (hn + bgL[c_loc * 6 + 5]));
      hfull = (obsL[r_loc] > 0.0f) ? ((1.0f - zgg) * ng + zgg * hbc) : hbc;
      outH[r_loc * 8 + c_loc] = (_Float16)hfull;
    }
    __syncthreads();
    if (tid < 128) cohS(((unsigned long long*)hA_cur) + oub + tid, outU[tid]);
    bar_arrive(a.bar, rg);
    if (t + 1 < Tn) {                              // X/M prefetch for t+1 hides b4 wait
      if (tid >= 64 && tid < 96)        xrowL[tid - 64] = a.X[((size_t)(t + 1) * Bn + g) * Dn + (tid - 64)];
      else if (tid >= 96 && tid < 128)  mrowL[tid - 96] = a.M[((size_t)(t + 1) * Bn + g) * Dn + (tid - 96)];
    }
    bar_wait(a.bar, rg, ep);
  }

  do_clf(slabp(0, (Tn - 1) & 3), Tn - 1);
}

extern "C" void kernel_launch(void* const* d_in, const int* in_sizes, int n_in,
                              void* d_out, int out_size, void* d_ws, size_t ws_size,
                              hipStream_t stream) {
  char* ws = (char*)d_ws;

  CoopArgs a;
  a.cov  = (const float*)d_in[0];
  a.X    = (const float*)d_in[1];
  a.M    = (const float*)d_in[2];
  a.Wc1  = (const float*)d_in[3];  a.bc1 = (const float*)d_in[4];
  a.Wc2  = (const float*)d_in[5];  a.bc2 = (const float*)d_in[6];
  a.Whr  = (const float*)d_in[7];  a.Whz = (const float*)d_in[8];  a.Whh = (const float*)d_in[9];
  const float* Wp1 = (const float*)d_in[10]; a.bp1 = (const float*)d_in[11];
  const float* Wp2 = (const float*)d_in[12]; a.bp2 = (const float*)d_in[13];
  a.w_prep = (const float*)d_in[14]; a.bias_prep = (const float*)d_in[15];
  a.W_ih = (const float*)d_in[16]; a.W_hh = (const float*)d_in[17];
  a.b_ih = (const float*)d_in[18]; a.b_hh = (const float*)d_in[19];
  const float* Wclf1 = (const float*)d_in[20]; a.bclf1 = (const float*)d_in[21];
  a.Wclf2 = (const float*)d_in[22]; a.bclf2 = (const float*)d_in[23];

  _Float16* pk = (_Float16*)ws;
  a.Wp1Q   = (const uint4*)(pk + PK_WP1);
  a.Wp2Q   = (const uint4*)(pk + PK_WP2);
  a.Wclf1Q = (const uint4*)(pk + PK_WCLF1);
  a.act = ws + WS_ACT;
  a.obs = (float*)(ws + WS_OBS);
  a.bar = (unsigned*)(ws + WS_BAR);
  a.out = (float*)d_out;

  PrepArgs p;
  p.Wp1 = Wp1; p.Wp2 = Wp2; p.Wclf1 = Wclf1;
  p.dst = pk; p.bar = a.bar;
  prep_pack_kernel<<<(PK_TOTAL + 255) / 256, 256, 0, stream>>>(p);
  gruode_coop<<<Bn, NT, 0, stream>>>(a);
}